// Round 3
// baseline (3050.606 us; speedup 1.0000x reference)
//
#include <hip/hip_runtime.h>
#include <hip/hip_bf16.h>

typedef __attribute__((ext_vector_type(8))) short short8;
typedef __attribute__((ext_vector_type(4))) float float4v;
typedef __attribute__((ext_vector_type(4))) int int4v;

__device__ __forceinline__ float sigmoidf_(float x) {
  return __fdividef(1.f, 1.f + __expf(-x));
}
__device__ __forceinline__ float tanhf_(float x) {
  float e = __expf(2.f * x);
  return 1.f - __fdividef(2.f, e + 1.f);
}
__device__ __forceinline__ float bflo(unsigned int v) {
  return __uint_as_float(v << 16);
}
__device__ __forceinline__ float bfhi(unsigned int v) {
  return __uint_as_float(v & 0xffff0000u);
}
// barrier that waits only LDS counts -- skips the vmcnt(0) drain
__device__ __forceinline__ void barrier_lgkm() {
  asm volatile("s_waitcnt lgkmcnt(0)\n\ts_barrier" ::: "memory");
}

__device__ __forceinline__ unsigned int pack4_(float4 v, float inv) {
  int b0 = (int)rintf(v.x * inv), b1 = (int)rintf(v.y * inv);
  int b2 = (int)rintf(v.z * inv), b3 = (int)rintf(v.w * inv);
  return (unsigned int)((b0 & 0xff) | ((b1 & 0xff) << 8) | ((b2 & 0xff) << 16) |
                        ((b3 & 0xff) << 24));
}

__device__ __forceinline__ unsigned short bf16bits_(float v) {
  __hip_bfloat16 b = __float2bfloat16(v);
  return *(unsigned short*)&b;
}

// ---------------------------------------------------------------------------
// Kernel Q: one-time int8 weight quantization. One wave per gate row.
// wq layout: row-major, 64 u32 (256 i8 along K) per gate-row.
// ---------------------------------------------------------------------------
__global__ __launch_bounds__(256) void wquant_kernel(
    const float* __restrict__ whh_f, const float* __restrict__ whh_b,
    unsigned int* __restrict__ wq, float* __restrict__ wsc) {
  const int wave_g = blockIdx.x * 4 + (threadIdx.x >> 6);
  const int lane = threadIdx.x & 63;
  const int dir = wave_g >> 10, row = wave_g & 1023;
  const float* __restrict__ src = (dir ? whh_b : whh_f) + (size_t)row * 256;
  float4 v = ((const float4*)src)[lane];
  float mx = fmaxf(fmaxf(fabsf(v.x), fabsf(v.y)), fmaxf(fabsf(v.z), fabsf(v.w)));
#pragma unroll
  for (int k = 32; k >= 1; k >>= 1) mx = fmaxf(mx, __shfl_xor(mx, k, 64));
  float inv = (mx > 0.f) ? __fdividef(127.f, mx) : 0.f;
  wq[(size_t)wave_g * 64 + lane] = pack4_(v, inv);
  if (lane == 0) wsc[wave_g] = (mx > 0.f) ? (mx / (127.f * 127.f)) : 0.f;
}

// ---------------------------------------------------------------------------
// Kernel A: projected embedding tables. M-tile 128.
// Stored at out[m*2048 + dir*1024 + u*4 + gate]  ([row][dir][unit][i,f,g,o]).
// ---------------------------------------------------------------------------
__global__ __launch_bounds__(256) void proj_gemm(
    const float* __restrict__ A, int rowsA, int Kdim, int col_off,
    const float* __restrict__ wf, const float* __restrict__ wb,
    const float* __restrict__ bf1, const float* __restrict__ bf2,
    const float* __restrict__ bb1, const float* __restrict__ bb2,
    __hip_bfloat16* __restrict__ out, int add_bias) {
  __shared__ __align__(16) __hip_bfloat16 As[128][40];
  __shared__ __align__(16) __hip_bfloat16 Bs[256][40];
  const int tid = threadIdx.x;
  const int m0 = blockIdx.x * 128, n0 = blockIdx.y * 256;
  const int lane = tid & 63, wave = tid >> 6;
  const int quad = lane >> 4, lm = lane & 15;
  float4v acc[2][16] = {};
  const int ksteps = (Kdim + 31) >> 5;
  const int r2 = tid >> 1, cbase = (tid & 1) << 4;
  const int rb = tid >> 4, cb = (tid & 15) * 2;
  for (int ks = 0; ks < ksteps; ++ks) {
    const int k0 = ks << 5;
#pragma unroll
    for (int e2 = 0; e2 < 8; ++e2) {
      int kk = k0 + cbase + 2 * e2;
      float b0 = 0.f, b1 = 0.f;
      if (m0 + r2 < rowsA && kk < Kdim) {
        float2 v = *(const float2*)(A + (size_t)(m0 + r2) * Kdim + kk);
        b0 = v.x;
        b1 = v.y;
      }
      As[r2][cbase + 2 * e2] = __float2bfloat16(b0);
      As[r2][cbase + 2 * e2 + 1] = __float2bfloat16(b1);
    }
#pragma unroll
    for (int j = 0; j < 16; ++j) {
      int n = n0 + rb + 16 * j;
      const float* __restrict__ wrow =
          (n < 1024) ? (wf + n * 450 + col_off) : (wb + (n - 1024) * 450 + col_off);
      int kk = k0 + cb;
      float b0 = 0.f, b1 = 0.f;
      if (kk < Kdim) {
        float2 v = *(const float2*)(wrow + kk);
        b0 = v.x;
        b1 = v.y;
      }
      Bs[rb + 16 * j][cb] = __float2bfloat16(b0);
      Bs[rb + 16 * j][cb + 1] = __float2bfloat16(b1);
    }
    __syncthreads();
    short8 af0 = *(const short8*)(&As[wave * 32 + lm][quad * 8]);
    short8 af1 = *(const short8*)(&As[wave * 32 + 16 + lm][quad * 8]);
#pragma unroll
    for (int t = 0; t < 16; ++t) {
      short8 bf = *(const short8*)(&Bs[t * 16 + lm][quad * 8]);
      acc[0][t] = __builtin_amdgcn_mfma_f32_16x16x32_bf16(af0, bf, acc[0][t], 0, 0, 0);
      acc[1][t] = __builtin_amdgcn_mfma_f32_16x16x32_bf16(af1, bf, acc[1][t], 0, 0, 0);
    }
    __syncthreads();
  }
#pragma unroll
  for (int mg = 0; mg < 2; ++mg) {
#pragma unroll
    for (int t = 0; t < 16; ++t) {
#pragma unroll
      for (int rr = 0; rr < 4; ++rr) {
        int m = m0 + wave * 32 + mg * 16 + quad * 4 + rr;
        int col = n0 + t * 16 + lm;
        if (m < rowsA) {
          float v = acc[mg][t][rr];
          if (add_bias)
            v += (col < 1024) ? (bf1[col] + bf2[col]) : (bb1[col - 1024] + bb2[col - 1024]);
          int dir = col >> 10, rq = col & 1023;
          int gate = rq >> 8, u = rq & 255;
          out[m * 2048 + dir * 1024 + u * 4 + gate] = __float2bfloat16(v);
        }
      }
    }
  }
}

// ---------------------------------------------------------------------------
// Kernel B (R16): batched BiLSTM recurrence via int8 MFMA.
// 16 blocks = 2 dir x 8 batch-groups of 16; 512 threads (8 waves, 2/SIMD).
// Per step per block: D[1024 gate-rows, 16 batches] = Wq(i8) x Hq(i8)^T as
// 256 x v_mfma_i32_16x16x64_i8 (exact i32 accumulation == dot4 numerics).
// Wave w owns rows {g*256 + w*32 + j, j<32}: 8 M-tiles x 4 K-tiles = 128
// weight VGPRs (MFMA reads AGPRs natively -> no residency fight).
// D layout (verified via proj_gemm in this file): row = tilebase+quad*4+rr,
// col = batch = lane&15 -> each lane owns 8 units x 4 gates of ONE batch,
// gate combine fully lane-local; c-state in 8 VGPRs.
// h exchanged per step through padded LDS (stride 272B); bf16 h ring (4
// steps) flushed to h_glob every 4 steps.
// ---------------------------------------------------------------------------
__global__ __launch_bounds__(512, 2) void lstm_kernel(
    const unsigned int* __restrict__ wq, const float* __restrict__ wsc,
    const int* __restrict__ x, const int* __restrict__ ptags, const int* __restrict__ gtags,
    const char* __restrict__ char_proj, const char* __restrict__ pin_proj,
    const char* __restrict__ tag_proj, __hip_bfloat16* __restrict__ h_out) {
  extern __shared__ __align__(16) char smem[];
  // [0, 8704): hq int8 double buffer: 2 x 16 batches x 272 (256 units + pad)
  // [8704, 42496): hist bf16 ring: 4 steps x 16 batches x 528 B (264 bf16)
  // [42496, 46592): wsc staged: 1024 floats
  char* hqb = smem;
  char* histb = smem + 8704;
  float* wscL = (float*)(smem + 42496);

  const int tid = threadIdx.x;
  const int w = tid >> 6, lane = tid & 63;
  const int lm = lane & 15, quad = lane >> 4;
  const int blk = blockIdx.x;
  const int dir = blk >> 3, bg = blk & 7;
  const int bb = bg * 16 + lm;  // this lane's batch
  const int b512 = bb * 512;

  // stage scales + zero hq
  for (int i = tid; i < 1024; i += 512) wscL[i] = wsc[dir * 1024 + i];
  for (int i = tid; i < 2176; i += 512) ((unsigned int*)hqb)[i] = 0u;

  // load weight fragments: Wf[g][h][kt], row = g*256 + w*32 + h*16 + lm
  const unsigned int* __restrict__ wqd = wq + (size_t)dir * 65536;
  int4v Wf[4][2][4];
#pragma unroll
  for (int g = 0; g < 4; ++g)
#pragma unroll
    for (int h = 0; h < 2; ++h) {
      const int row = g * 256 + w * 32 + h * 16 + lm;
#pragma unroll
      for (int kt = 0; kt < 4; ++kt)
        Wf[g][h][kt] = *(const int4v*)(wqd + row * 64 + kt * 16 + quad * 4);
    }
  __syncthreads();

  float c8[2][4] = {};  // c-state [h][rr]
  const size_t preoff0 = (size_t)dir * 2048 + (size_t)(w * 32 + quad * 4) * 8;

  int t = dir ? 511 : 0;
  int xi = x[b512 + t], pi = ptags[b512 + t], gi_ = gtags[b512 + t];

  for (int s = 0; s < 512; ++s) {
    const int cur = s & 1, nxt = cur ^ 1;
    const char* cb0 = char_proj + (size_t)xi * 4096 + preoff0;
    const char* pb0 = pin_proj + (size_t)pi * 4096 + preoff0;
    const char* tb0 = tag_proj + (size_t)gi_ * 4096 + preoff0;
    // h=0 pre gathers (consumed after MFMA)
    uint4 pc0[2], pp0[2], pt0[2];
    pc0[0] = *(const uint4*)(cb0);      pc0[1] = *(const uint4*)(cb0 + 16);
    pp0[0] = *(const uint4*)(pb0);      pp0[1] = *(const uint4*)(pb0 + 16);
    pt0[0] = *(const uint4*)(tb0);      pt0[1] = *(const uint4*)(tb0 + 16);
    // prefetch next-step indices
    int sn = (s + 1 < 512) ? s + 1 : 511;
    int tn = dir ? 511 - sn : sn;
    int xin = x[b512 + tn], pin_ = ptags[b512 + tn], gin = gtags[b512 + tn];

    // MFMA: D[row, batch] over 4 K-tiles
    int4v acc[4][2] = {};
    const char* hqcur = hqb + cur * 4352 + lm * 272;
#pragma unroll
    for (int kt = 0; kt < 4; ++kt) {
      int4v Bv = *(const int4v*)(hqcur + kt * 64 + quad * 16);
#pragma unroll
      for (int g = 0; g < 4; ++g)
#pragma unroll
        for (int h = 0; h < 2; ++h)
          acc[g][h] = __builtin_amdgcn_mfma_i32_16x16x64_i8(Wf[g][h][kt], Bv, acc[g][h], 0, 0, 0);
    }
    // h=1 pre gathers (latency hidden under h=0 gate math)
    uint4 pc1[2], pp1[2], pt1[2];
    pc1[0] = *(const uint4*)(cb0 + 128); pc1[1] = *(const uint4*)(cb0 + 144);
    pp1[0] = *(const uint4*)(pb0 + 128); pp1[1] = *(const uint4*)(pb0 + 144);
    pt1[0] = *(const uint4*)(tb0 + 128); pt1[1] = *(const uint4*)(tb0 + 144);

    char* hqn = hqb + nxt * 4352 + lm * 272 + w * 32 + quad * 4;
    char* histp = histb + (s & 3) * 8448 + lm * 528 + (size_t)(w * 32 + quad * 4) * 2;

#pragma unroll
    for (int h = 0; h < 2; ++h) {
      const float4 s0 = *(const float4*)&wscL[0 * 256 + w * 32 + h * 16 + quad * 4];
      const float4 s1 = *(const float4*)&wscL[1 * 256 + w * 32 + h * 16 + quad * 4];
      const float4 s2 = *(const float4*)&wscL[2 * 256 + w * 32 + h * 16 + quad * 4];
      const float4 s3 = *(const float4*)&wscL[3 * 256 + w * 32 + h * 16 + quad * 4];
      unsigned int hqpack = 0, hist0 = 0, hist1 = 0;
#pragma unroll
      for (int rr = 0; rr < 4; ++rr) {
        uint4 cc = h ? pc1[rr >> 1] : pc0[rr >> 1];
        uint4 pp = h ? pp1[rr >> 1] : pp0[rr >> 1];
        uint4 tt = h ? pt1[rr >> 1] : pt0[rr >> 1];
        unsigned lo_c = (rr & 1) ? cc.z : cc.x, hi_c = (rr & 1) ? cc.w : cc.y;
        unsigned lo_p = (rr & 1) ? pp.z : pp.x, hi_p = (rr & 1) ? pp.w : pp.y;
        unsigned lo_t = (rr & 1) ? tt.z : tt.x, hi_t = (rr & 1) ? tt.w : tt.y;
        float sci = (rr == 0) ? s0.x : (rr == 1) ? s0.y : (rr == 2) ? s0.z : s0.w;
        float scf = (rr == 0) ? s1.x : (rr == 1) ? s1.y : (rr == 2) ? s1.z : s1.w;
        float scg = (rr == 0) ? s2.x : (rr == 1) ? s2.y : (rr == 2) ? s2.z : s2.w;
        float sco = (rr == 0) ? s3.x : (rr == 1) ? s3.y : (rr == 2) ? s3.z : s3.w;
        float vi = bflo(lo_c) + bflo(lo_p) + bflo(lo_t) + (float)acc[0][h][rr] * sci;
        float vf = bfhi(lo_c) + bfhi(lo_p) + bfhi(lo_t) + (float)acc[1][h][rr] * scf;
        float vg = bflo(hi_c) + bflo(hi_p) + bflo(hi_t) + (float)acc[2][h][rr] * scg;
        float vo = bfhi(hi_c) + bfhi(hi_p) + bfhi(hi_t) + (float)acc[3][h][rr] * sco;
        float c = sigmoidf_(vf) * c8[h][rr] + sigmoidf_(vi) * tanhf_(vg);
        c8[h][rr] = c;
        float hv = sigmoidf_(vo) * tanhf_(c);
        hqpack |= ((unsigned)((int)rintf(hv * 127.f) & 0xff)) << (8 * rr);
        unsigned hb = (unsigned)bf16bits_(hv);
        if (rr < 2) hist0 |= hb << (16 * rr);
        else hist1 |= hb << (16 * (rr - 2));
      }
      *(unsigned int*)(hqn + h * 16) = hqpack;           // i8 h for next step
      *(uint2*)(histp + h * 32) = make_uint2(hist0, hist1);  // bf16 history
    }
    barrier_lgkm();
    if ((s & 3) == 3) {
      // flush 4 steps x 16 batches x 512B from hist ring to h_glob
      const int row = tid >> 3;            // 64 rows
      const int sr = row >> 4, bi = row & 15;
      const int step_r = s - 3 + sr;
      const int t_r = dir ? 511 - step_r : step_r;
      const char* src = histb + (size_t)(sr * 16 + bi) * 528 + (tid & 7) * 64;
      char* dst = (char*)h_out +
                  ((size_t)((dir * 128 + bg * 16 + bi) * 512 + t_r) * 256) * 2 + (tid & 7) * 64;
#pragma unroll
      for (int j = 0; j < 4; ++j)
        ((uint4*)dst)[j] = ((const uint4*)src)[j];
      barrier_lgkm();  // protect ring slot 0 from next step's writes
    }
    xi = xin; pi = pin_; gi_ = gin; t = tn;
  }
}

// ---------------------------------------------------------------------------
// Kernel C: emissions GEMM. em[b*512+t][k] = Hcat[n]·w_out[k] + b_out[k]
// ---------------------------------------------------------------------------
__global__ __launch_bounds__(256) void emis_kernel(
    const __hip_bfloat16* __restrict__ h_glob, const float* __restrict__ w_out,
    const float* __restrict__ b_out, float* __restrict__ em) {
  __shared__ __align__(16) __hip_bfloat16 As[64][40];
  __shared__ __align__(16) __hip_bfloat16 Bs[32][40];
  const int tid = threadIdx.x;
  const int n0 = blockIdx.x * 64;
  const int lane = tid & 63, wave = tid >> 6, quad = lane >> 4, lm = lane & 15;
  float4v acc[2] = {};
  const int r = tid >> 2, c0 = (tid & 3) << 3;
  const int rb = tid >> 3, cb = (tid & 7) << 2;
  for (int ks = 0; ks < 16; ++ks) {
    const int j0 = ks * 32;
    const int dirk = j0 >> 8, jin = j0 & 255;
    const int n = n0 + r, bb = n >> 9, tt = n & 511;
    const uint4* src =
        (const uint4*)(h_glob + ((size_t)(dirk * 128 + bb) * 512 + tt) * 256 + jin + c0);
    *(uint4*)(&As[r][c0]) = *src;
#pragma unroll
    for (int e = 0; e < 4; ++e) {
      float v = (rb < 20) ? w_out[rb * 512 + j0 + cb + e] : 0.f;
      Bs[rb][cb + e] = __float2bfloat16(v);
    }
    __syncthreads();
    short8 af = *(const short8*)(&As[wave * 16 + lm][quad * 8]);
#pragma unroll
    for (int t2 = 0; t2 < 2; ++t2) {
      short8 bf = *(const short8*)(&Bs[t2 * 16 + lm][quad * 8]);
      acc[t2] = __builtin_amdgcn_mfma_f32_16x16x32_bf16(af, bf, acc[t2], 0, 0, 0);
    }
    __syncthreads();
  }
#pragma unroll
  for (int t2 = 0; t2 < 2; ++t2) {
#pragma unroll
    for (int rr = 0; rr < 4; ++rr) {
      int col = t2 * 16 + lm;
      if (col < 20) {
        int n = n0 + wave * 16 + quad * 4 + rr;
        em[(size_t)n * 20 + col] = acc[t2][rr] + b_out[col];
      }
    }
  }
}

// ---------------------------------------------------------------------------
// Kernel D: CRF forward NLL. 1 wave per batch element, readlane broadcast.
// ---------------------------------------------------------------------------
__global__ __launch_bounds__(64) void crf_kernel(
    const float* __restrict__ em, const int* __restrict__ y,
    const float* __restrict__ start_trans, const float* __restrict__ end_trans,
    const float* __restrict__ trans, float* __restrict__ partials) {
  const int b = blockIdx.x;
  const int lane = threadIdx.x;
  const int jj = lane < 20 ? lane : 19;
  const bool act = lane < 20;
  const float* __restrict__ emb = em + (size_t)b * 512 * 20;
  const int* __restrict__ yb = y + b * 512;

  float s_part = 0.f;
#pragma unroll
  for (int i = 0; i < 8; ++i) {
    int t = lane + 64 * i;
    int yc = yb[t];
    float v = emb[t * 20 + yc];
    v += (t == 0) ? start_trans[yc] : trans[yb[t - 1] * 20 + yc];
    s_part += v;
  }
#pragma unroll
  for (int k = 32; k >= 1; k >>= 1) s_part += __shfl_xor(s_part, k, 64);
  float score = s_part + end_trans[yb[511]];

  float ET[20];
#pragma unroll
  for (int i = 0; i < 20; ++i) ET[i] = __expf(trans[i * 20 + jj]);
  float alpha = act ? (start_trans[jj] + emb[jj]) : -1e30f;
  float P = alpha;
#pragma unroll
  for (int k = 32; k >= 1; k >>= 1) P = fmaxf(P, __shfl_xor(P, k, 64));

  float eC = emb[1 * 20 + jj];
  float eN = emb[2 * 20 + jj];
  for (int t = 1; t < 512; ++t) {
    if ((t & 15) == 0) {
      P = alpha;
#pragma unroll
      for (int k = 32; k >= 1; k >>= 1) P = fmaxf(P, __shfl_xor(P, k, 64));
    }
    float ex = __expf(alpha - P);
    float s0 = 0.f, s1 = 0.f;
#pragma unroll
    for (int i = 0; i < 20; i += 2) {
      float e0 = __int_as_float(__builtin_amdgcn_readlane(__float_as_int(ex), i));
      float e1 = __int_as_float(__builtin_amdgcn_readlane(__float_as_int(ex), i + 1));
      s0 = fmaf(e0, ET[i], s0);
      s1 = fmaf(e1, ET[i + 1], s1);
    }
    int tf = t + 2 < 512 ? t + 2 : 511;
    float eF = emb[tf * 20 + jj];
    if (act) alpha = P + __logf(s0 + s1) + eC;
    eC = eN;
    eN = eF;
  }
  float v = act ? (alpha + end_trans[jj]) : -1e30f;
  float Pz = v;
#pragma unroll
  for (int k = 32; k >= 1; k >>= 1) Pz = fmaxf(Pz, __shfl_xor(Pz, k, 64));
  float e2 = __expf(v - Pz);
#pragma unroll
  for (int k = 32; k >= 1; k >>= 1) e2 += __shfl_xor(e2, k, 64);
  float logZ = Pz + __logf(e2);
  if (lane == 0) partials[b] = logZ - score;
}

__global__ __launch_bounds__(128) void reduce_kernel(const float* __restrict__ partials,
                                                     float* __restrict__ out) {
  const int tid = threadIdx.x;
  float v = partials[tid];
#pragma unroll
  for (int k = 32; k >= 1; k >>= 1) v += __shfl_xor(v, k, 64);
  __shared__ float tmp[2];
  if ((tid & 63) == 0) tmp[tid >> 6] = v;
  __syncthreads();
  if (tid == 0) out[0] = tmp[0] + tmp[1];
}

// ---------------------------------------------------------------------------
extern "C" void kernel_launch(void* const* d_in, const int* in_sizes, int n_in,
                              void* d_out, int out_size, void* d_ws, size_t ws_size,
                              hipStream_t stream) {
  const int* x = (const int*)d_in[0];
  const int* y = (const int*)d_in[1];
  const int* pre_tags = (const int*)d_in[2];
  const int* pinyin_tags = (const int*)d_in[3];
  const float* char_emb = (const float*)d_in[5];
  const float* tag_emb = (const float*)d_in[6];
  const float* pinyin_emb = (const float*)d_in[7];
  const float* w_ih_f = (const float*)d_in[8];
  const float* w_hh_f = (const float*)d_in[9];
  const float* b_ih_f = (const float*)d_in[10];
  const float* b_hh_f = (const float*)d_in[11];
  const float* w_ih_b = (const float*)d_in[12];
  const float* w_hh_b = (const float*)d_in[13];
  const float* b_ih_b = (const float*)d_in[14];
  const float* b_hh_b = (const float*)d_in[15];
  const float* w_out = (const float*)d_in[16];
  const float* b_out = (const float*)d_in[17];
  const float* start_trans = (const float*)d_in[18];
  const float* end_trans = (const float*)d_in[19];
  const float* trans = (const float*)d_in[20];

  char* ws = (char*)d_ws;
  __hip_bfloat16* char_proj = (__hip_bfloat16*)(ws);            // 10002*2048*2 = 40968192
  __hip_bfloat16* pin_proj = (__hip_bfloat16*)(ws + 40968192);  // 500*2048*2  = 2048000
  __hip_bfloat16* tag_proj = (__hip_bfloat16*)(ws + 43016192);  // 20*2048*2   = 81920
  __hip_bfloat16* h_glob = (__hip_bfloat16*)(ws + 43098112);    // 2*128*512*256*2 = 67108864
  float* em = (float*)(ws + 110206976);                         // 65536*20*4 = 5242880
  float* partials = (float*)(ws + 115449856);                   // 128*4
  // wq/wsc live inside the em region (em is written only after lstm finishes)
  unsigned int* wq = (unsigned int*)(ws + 110206976);           // 2*1024*64*4 = 524288
  float* wsc = (float*)(ws + 110206976 + 524288);               // 2048*4

  wquant_kernel<<<512, 256, 0, stream>>>(w_hh_f, w_hh_b, wq, wsc);

  proj_gemm<<<dim3(79, 8), 256, 0, stream>>>(char_emb, 10002, 300, 0, w_ih_f, w_ih_b,
                                             nullptr, nullptr, nullptr, nullptr, char_proj, 0);
  proj_gemm<<<dim3(4, 8), 256, 0, stream>>>(pinyin_emb, 500, 100, 300, w_ih_f, w_ih_b,
                                            nullptr, nullptr, nullptr, nullptr, pin_proj, 0);
  proj_gemm<<<dim3(1, 8), 256, 0, stream>>>(tag_emb, 20, 50, 400, w_ih_f, w_ih_b,
                                            b_ih_f, b_hh_f, b_ih_b, b_hh_b, tag_proj, 1);

  const int lstm_lds = 46592;  // 8704 hq + 33792 hist + 4096 wsc
  hipFuncSetAttribute((const void*)lstm_kernel, hipFuncAttributeMaxDynamicSharedMemorySize,
                      lstm_lds);
  lstm_kernel<<<16, 512, lstm_lds, stream>>>(wq, wsc, x, pinyin_tags, pre_tags,
                                             (const char*)char_proj, (const char*)pin_proj,
                                             (const char*)tag_proj, h_glob);

  emis_kernel<<<1024, 256, 0, stream>>>(h_glob, w_out, b_out, em);
  crf_kernel<<<128, 64, 0, stream>>>(em, y, start_trans, end_trans, trans, partials);
  reduce_kernel<<<1, 128, 0, stream>>>(partials, (float*)d_out);
}

// Round 4
// 1285.545 us; speedup vs baseline: 2.3730x; 2.3730x over previous
//
#include <hip/hip_runtime.h>
#include <hip/hip_bf16.h>

typedef __attribute__((ext_vector_type(8))) short short8;
typedef __attribute__((ext_vector_type(4))) float float4v;

#if __has_builtin(__builtin_amdgcn_sdot4)
#define DOT4(a, b, c) __builtin_amdgcn_sdot4((int)(a), (int)(b), (c), false)
#else
__device__ __forceinline__ int dot4_(int a, int b, int c) {
  c += (int)(signed char)(a) * (int)(signed char)(b);
  c += (int)(signed char)(a >> 8) * (int)(signed char)(b >> 8);
  c += (int)(signed char)(a >> 16) * (int)(signed char)(b >> 16);
  c += (a >> 24) * (b >> 24);
  return c;
}
#define DOT4(a, b, c) dot4_((int)(a), (int)(b), (c))
#endif

__device__ __forceinline__ float sigmoidf_(float x) {
  return __fdividef(1.f, 1.f + __expf(-x));
}
__device__ __forceinline__ float tanhf_(float x) {
  float e = __expf(2.f * x);
  return 1.f - __fdividef(2.f, e + 1.f);
}
__device__ __forceinline__ float bflo(unsigned int v) {
  return __uint_as_float(v << 16);
}
__device__ __forceinline__ float bfhi(unsigned int v) {
  return __uint_as_float(v & 0xffff0000u);
}
// barrier that waits only LDS counts (h ordering) -- skips the vmcnt(0) drain
__device__ __forceinline__ void barrier_lgkm() {
  asm volatile("s_waitcnt lgkmcnt(0)\n\ts_barrier" ::: "memory");
}

// quad (4-lane) butterflies via DPP quad_perm (VALU, not DS pipe)
template <int CTRL>
__device__ __forceinline__ int qadd_i(int v) {
  return v + __builtin_amdgcn_update_dpp(0, v, CTRL, 0xF, 0xF, true);
}
#define XOR1 0xB1  // quad_perm [1,0,3,2]
#define XOR2 0x4E  // quad_perm [2,3,0,1]

__device__ __forceinline__ unsigned int pack4_(float4 v, float inv) {
  int b0 = (int)rintf(v.x * inv), b1 = (int)rintf(v.y * inv);
  int b2 = (int)rintf(v.z * inv), b3 = (int)rintf(v.w * inv);
  return (unsigned int)((b0 & 0xff) | ((b1 & 0xff) << 8) | ((b2 & 0xff) << 16) |
                        ((b3 & 0xff) << 24));
}

// ---------------------------------------------------------------------------
// Kernel Q: one-time int8 weight quantization. One wave per gate row.
// ---------------------------------------------------------------------------
__global__ __launch_bounds__(256) void wquant_kernel(
    const float* __restrict__ whh_f, const float* __restrict__ whh_b,
    unsigned int* __restrict__ wq, float* __restrict__ wsc) {
  const int wave_g = blockIdx.x * 4 + (threadIdx.x >> 6);
  const int lane = threadIdx.x & 63;
  const int dir = wave_g >> 10, row = wave_g & 1023;
  const float* __restrict__ src = (dir ? whh_b : whh_f) + (size_t)row * 256;
  float4 v = ((const float4*)src)[lane];
  float mx = fmaxf(fmaxf(fabsf(v.x), fabsf(v.y)), fmaxf(fabsf(v.z), fabsf(v.w)));
#pragma unroll
  for (int k = 32; k >= 1; k >>= 1) mx = fmaxf(mx, __shfl_xor(mx, k, 64));
  float inv = (mx > 0.f) ? __fdividef(127.f, mx) : 0.f;
  wq[(size_t)wave_g * 64 + lane] = pack4_(v, inv);
  if (lane == 0) wsc[wave_g] = (mx > 0.f) ? (mx / (127.f * 127.f)) : 0.f;
}

// ---------------------------------------------------------------------------
// Kernel A: projected embedding tables. M-tile 128.
// Stored at out[m*2048 + dir*1024 + u*4 + gate]  ([row][dir][unit][i,f,g,o]).
// ---------------------------------------------------------------------------
__global__ __launch_bounds__(256) void proj_gemm(
    const float* __restrict__ A, int rowsA, int Kdim, int col_off,
    const float* __restrict__ wf, const float* __restrict__ wb,
    const float* __restrict__ bf1, const float* __restrict__ bf2,
    const float* __restrict__ bb1, const float* __restrict__ bb2,
    __hip_bfloat16* __restrict__ out, int add_bias) {
  __shared__ __align__(16) __hip_bfloat16 As[128][40];
  __shared__ __align__(16) __hip_bfloat16 Bs[256][40];
  const int tid = threadIdx.x;
  const int m0 = blockIdx.x * 128, n0 = blockIdx.y * 256;
  const int lane = tid & 63, wave = tid >> 6;
  const int quad = lane >> 4, lm = lane & 15;
  float4v acc[2][16] = {};
  const int ksteps = (Kdim + 31) >> 5;
  const int r2 = tid >> 1, cbase = (tid & 1) << 4;
  const int rb = tid >> 4, cb = (tid & 15) * 2;
  for (int ks = 0; ks < ksteps; ++ks) {
    const int k0 = ks << 5;
#pragma unroll
    for (int e2 = 0; e2 < 8; ++e2) {
      int kk = k0 + cbase + 2 * e2;
      float b0 = 0.f, b1 = 0.f;
      if (m0 + r2 < rowsA && kk < Kdim) {
        float2 v = *(const float2*)(A + (size_t)(m0 + r2) * Kdim + kk);
        b0 = v.x;
        b1 = v.y;
      }
      As[r2][cbase + 2 * e2] = __float2bfloat16(b0);
      As[r2][cbase + 2 * e2 + 1] = __float2bfloat16(b1);
    }
#pragma unroll
    for (int j = 0; j < 16; ++j) {
      int n = n0 + rb + 16 * j;
      const float* __restrict__ wrow =
          (n < 1024) ? (wf + n * 450 + col_off) : (wb + (n - 1024) * 450 + col_off);
      int kk = k0 + cb;
      float b0 = 0.f, b1 = 0.f;
      if (kk < Kdim) {
        float2 v = *(const float2*)(wrow + kk);
        b0 = v.x;
        b1 = v.y;
      }
      Bs[rb + 16 * j][cb] = __float2bfloat16(b0);
      Bs[rb + 16 * j][cb + 1] = __float2bfloat16(b1);
    }
    __syncthreads();
    short8 af0 = *(const short8*)(&As[wave * 32 + lm][quad * 8]);
    short8 af1 = *(const short8*)(&As[wave * 32 + 16 + lm][quad * 8]);
#pragma unroll
    for (int t = 0; t < 16; ++t) {
      short8 bf = *(const short8*)(&Bs[t * 16 + lm][quad * 8]);
      acc[0][t] = __builtin_amdgcn_mfma_f32_16x16x32_bf16(af0, bf, acc[0][t], 0, 0, 0);
      acc[1][t] = __builtin_amdgcn_mfma_f32_16x16x32_bf16(af1, bf, acc[1][t], 0, 0, 0);
    }
    __syncthreads();
  }
#pragma unroll
  for (int mg = 0; mg < 2; ++mg) {
#pragma unroll
    for (int t = 0; t < 16; ++t) {
#pragma unroll
      for (int rr = 0; rr < 4; ++rr) {
        int m = m0 + wave * 32 + mg * 16 + quad * 4 + rr;
        int col = n0 + t * 16 + lm;
        if (m < rowsA) {
          float v = acc[mg][t][rr];
          if (add_bias)
            v += (col < 1024) ? (bf1[col] + bf2[col]) : (bb1[col - 1024] + bb2[col - 1024]);
          int dir = col >> 10, rq = col & 1023;
          int gate = rq >> 8, u = rq & 255;
          out[m * 2048 + dir * 1024 + u * 4 + gate] = __float2bfloat16(v);
        }
      }
    }
  }
}

// ---------------------------------------------------------------------------
// Kernel B (R17): BiLSTM recurrence, int8 dot4, 1024 threads/chain (16 waves
// -> 4 waves/SIMD). Thread map: q = tid>>2 owns unit q (4 gate-rows); e =
// tid&3 owns h-window [e*64, e*64+64). Per-thread weights = 4 rows x 16
// dwords = 64 VGPRs. A 1024-thread block REQUIRES VGPR <= 128 (4 waves/SIMD
// is the only valid residency), so the register cap and the residency target
// coincide -- the allocator cannot trade weight residency for a higher
// occupancy tier (R13: needed 192 got 132; R15: needed 128 got 84 -- both
// spilled because slack under the cap let it aim for a smaller tier; the
// reload path cost ~2000 cy/step of the measured 3341 vs a 512 cy dot4
// floor). Quad butterfly (XOR1/XOR2) sums over e; all 4 lanes of a quad
// redundantly compute unit q's gates; only e==0 writes h.
// Weights laundered through LDS via an opaque read-slot (values become
// non-rematerializable); scale-launder phase [0,4096) is separated from
// weight-launder [0,16384) by a real __syncthreads().
// ---------------------------------------------------------------------------
__global__ __launch_bounds__(1024, 4) void lstm_kernel(
    const unsigned int* __restrict__ wq, const float* __restrict__ wsc,
    const int* __restrict__ x, const int* __restrict__ ptags, const int* __restrict__ gtags,
    const char* __restrict__ char_proj, const char* __restrict__ pin_proj,
    const char* __restrict__ tag_proj, __hip_bfloat16* __restrict__ h_out) {
  extern __shared__ __align__(16) char smem[];
  __hip_bfloat16* hist = (__hip_bfloat16*)smem;    // 32*256*2 = 16384
  signed char* hb = (signed char*)(smem + 16384);  // 2*256 = 512

  const int tid = threadIdx.x;
  const int q = tid >> 2, e = tid & 3;
  const int chain = blockIdx.x;
  const int dir = chain >> 7;
  const int b = chain & 127;
  const int boff = b * 512;

  if (tid < 32) ((int4*)hb)[tid] = make_int4(0, 0, 0, 0);

  // opaque read-slot: equals tid at runtime, unprovable at compile time
  int rslot = tid;
  asm volatile("" : "+v"(rslot));

  const unsigned int* __restrict__ wqd = wq + (size_t)dir * 65536;
  const float* __restrict__ wscd = wsc + dir * 1024;

  // phase 1: scale launder in [0,4096) (hist region, clobbered in-loop)
  float sc4[4];
  {
    float* fl = (float*)smem;
#pragma unroll
    for (int g = 0; g < 4; ++g) {
      fl[tid] = wscd[g * 256 + q];
      sc4[g] = fl[rslot];
    }
  }
  __syncthreads();  // phases use overlapping LDS; real barrier between them

  // phase 2: weight launder, per-thread slot tid*16 in [0,16384)
  unsigned int Wreg[4][16];
  {
    uint4* lbuf = (uint4*)smem;
#pragma unroll
    for (int g = 0; g < 4; ++g) {
      const uint4* __restrict__ srcp = (const uint4*)(wqd + (g * 256 + q) * 64 + e * 16);
#pragma unroll
      for (int c = 0; c < 4; ++c) {
        lbuf[tid] = srcp[c];
        uint4 a = lbuf[rslot];
        Wreg[g][4 * c + 0] = a.x;
        Wreg[g][4 * c + 1] = a.y;
        Wreg[g][4 * c + 2] = a.z;
        Wreg[g][4 * c + 3] = a.w;
      }
    }
  }
  __syncthreads();

  const int pre_off = dir * 2048 + q * 8;  // byte offset into proj rows
  float cst = 0.f;

  // prefetch rotation: indices 2 steps ahead (scalar), gathers 1 step ahead
  int t_cur = dir ? 511 : 0;
  int t_nxt = dir ? 510 : 1;
  int xc = x[boff + t_cur], pc_i = ptags[boff + t_cur], gc_i = gtags[boff + t_cur];
  uint2 vc = *(const uint2*)(char_proj + (size_t)xc * 4096 + pre_off);
  uint2 vp = *(const uint2*)(pin_proj + (size_t)pc_i * 4096 + pre_off);
  uint2 vg = *(const uint2*)(tag_proj + (size_t)gc_i * 4096 + pre_off);
  int xn = x[boff + t_nxt], pn = ptags[boff + t_nxt], gn = gtags[boff + t_nxt];

  for (int s = 0; s < 512; ++s) {
    const uint2 cv = vc, pv = vp, gv = vg;
    const int t_fut = dir ? (t_nxt > 0 ? t_nxt - 1 : 0) : (t_nxt < 511 ? t_nxt + 1 : 511);
    vc = *(const uint2*)(char_proj + (size_t)xn * 4096 + pre_off);
    vp = *(const uint2*)(pin_proj + (size_t)pn * 4096 + pre_off);
    vg = *(const uint2*)(tag_proj + (size_t)gn * 4096 + pre_off);
    xn = x[boff + t_fut];
    pn = ptags[boff + t_fut];
    gn = gtags[boff + t_fut];

    const signed char* hbase = hb + (s & 1) * 256 + e * 64;
    int acc[4] = {0, 0, 0, 0};
#pragma unroll
    for (int c = 0; c < 4; ++c) {
      uint4 H = *(const uint4*)(hbase + c * 16);
#pragma unroll
      for (int g = 0; g < 4; ++g) {
        acc[g] = DOT4(Wreg[g][4 * c + 0], H.x, acc[g]);
        acc[g] = DOT4(Wreg[g][4 * c + 1], H.y, acc[g]);
        acc[g] = DOT4(Wreg[g][4 * c + 2], H.z, acc[g]);
        acc[g] = DOT4(Wreg[g][4 * c + 3], H.w, acc[g]);
      }
    }
#pragma unroll
    for (int g = 0; g < 4; ++g) {
      int v = qadd_i<XOR1>(acc[g]);
      acc[g] = qadd_i<XOR2>(v);
    }
    float gi = bflo(cv.x) + bflo(pv.x) + bflo(gv.x) + (float)acc[0] * sc4[0];
    float gf = bfhi(cv.x) + bfhi(pv.x) + bfhi(gv.x) + (float)acc[1] * sc4[1];
    float gg = bflo(cv.y) + bflo(pv.y) + bflo(gv.y) + (float)acc[2] * sc4[2];
    float go = bfhi(cv.y) + bfhi(pv.y) + bfhi(gv.y) + (float)acc[3] * sc4[3];
    cst = sigmoidf_(gf) * cst + sigmoidf_(gi) * tanhf_(gg);
    float hval = sigmoidf_(go) * tanhf_(cst);
    if (e == 0) {
      hb[((s + 1) & 1) * 256 + q] = (signed char)(int)rintf(hval * 127.f);
      hist[(s & 31) * 256 + q] = __float2bfloat16(hval);
    }
    barrier_lgkm();
    if ((s & 15) == 15) {
      if (tid < 512) {  // wave-uniform guard (waves 0-7); no barrier inside
        const int slotBase = (s & 31) & ~15;
        const int sBase = s - 15;
        const int row = tid >> 5;  // 16 steps x 32 uint4
        const int col16 = tid & 31;
        uint4 v = *(const uint4*)((const char*)hist + (slotBase + row) * 512 + col16 * 16);
        int step_r = sBase + row;
        int t_r = dir ? (511 - step_r) : step_r;
        *(uint4*)((char*)h_out + ((size_t)(chain * 512 + t_r) * 256) * 2 + col16 * 16) = v;
      }
    }
    t_cur = t_nxt;
    t_nxt = t_fut;
  }
}

// ---------------------------------------------------------------------------
// Kernel C: emissions GEMM. em[b*512+t][k] = Hcat[n]·w_out[k] + b_out[k]
// ---------------------------------------------------------------------------
__global__ __launch_bounds__(256) void emis_kernel(
    const __hip_bfloat16* __restrict__ h_glob, const float* __restrict__ w_out,
    const float* __restrict__ b_out, float* __restrict__ em) {
  __shared__ __align__(16) __hip_bfloat16 As[64][40];
  __shared__ __align__(16) __hip_bfloat16 Bs[32][40];
  const int tid = threadIdx.x;
  const int n0 = blockIdx.x * 64;
  const int lane = tid & 63, wave = tid >> 6, quad = lane >> 4, lm = lane & 15;
  float4v acc[2] = {};
  const int r = tid >> 2, c0 = (tid & 3) << 3;
  const int rb = tid >> 3, cb = (tid & 7) << 2;
  for (int ks = 0; ks < 16; ++ks) {
    const int j0 = ks * 32;
    const int dirk = j0 >> 8, jin = j0 & 255;
    const int n = n0 + r, bb = n >> 9, tt = n & 511;
    const uint4* src =
        (const uint4*)(h_glob + ((size_t)(dirk * 128 + bb) * 512 + tt) * 256 + jin + c0);
    *(uint4*)(&As[r][c0]) = *src;
#pragma unroll
    for (int e = 0; e < 4; ++e) {
      float v = (rb < 20) ? w_out[rb * 512 + j0 + cb + e] : 0.f;
      Bs[rb][cb + e] = __float2bfloat16(v);
    }
    __syncthreads();
    short8 af = *(const short8*)(&As[wave * 16 + lm][quad * 8]);
#pragma unroll
    for (int t2 = 0; t2 < 2; ++t2) {
      short8 bf = *(const short8*)(&Bs[t2 * 16 + lm][quad * 8]);
      acc[t2] = __builtin_amdgcn_mfma_f32_16x16x32_bf16(af, bf, acc[t2], 0, 0, 0);
    }
    __syncthreads();
  }
#pragma unroll
  for (int t2 = 0; t2 < 2; ++t2) {
#pragma unroll
    for (int rr = 0; rr < 4; ++rr) {
      int col = t2 * 16 + lm;
      if (col < 20) {
        int n = n0 + wave * 16 + quad * 4 + rr;
        em[(size_t)n * 20 + col] = acc[t2][rr] + b_out[col];
      }
    }
  }
}

// ---------------------------------------------------------------------------
// Kernel D: CRF forward NLL. 1 wave per batch element, readlane broadcast.
// ---------------------------------------------------------------------------
__global__ __launch_bounds__(64) void crf_kernel(
    const float* __restrict__ em, const int* __restrict__ y,
    const float* __restrict__ start_trans, const float* __restrict__ end_trans,
    const float* __restrict__ trans, float* __restrict__ partials) {
  const int b = blockIdx.x;
  const int lane = threadIdx.x;
  const int jj = lane < 20 ? lane : 19;
  const bool act = lane < 20;
  const float* __restrict__ emb = em + (size_t)b * 512 * 20;
  const int* __restrict__ yb = y + b * 512;

  float s_part = 0.f;
#pragma unroll
  for (int i = 0; i < 8; ++i) {
    int t = lane + 64 * i;
    int yc = yb[t];
    float v = emb[t * 20 + yc];
    v += (t == 0) ? start_trans[yc] : trans[yb[t - 1] * 20 + yc];
    s_part += v;
  }
#pragma unroll
  for (int k = 32; k >= 1; k >>= 1) s_part += __shfl_xor(s_part, k, 64);
  float score = s_part + end_trans[yb[511]];

  float ET[20];
#pragma unroll
  for (int i = 0; i < 20; ++i) ET[i] = __expf(trans[i * 20 + jj]);
  float alpha = act ? (start_trans[jj] + emb[jj]) : -1e30f;
  float P = alpha;
#pragma unroll
  for (int k = 32; k >= 1; k >>= 1) P = fmaxf(P, __shfl_xor(P, k, 64));

  float eC = emb[1 * 20 + jj];
  float eN = emb[2 * 20 + jj];
  for (int t = 1; t < 512; ++t) {
    if ((t & 15) == 0) {
      P = alpha;
#pragma unroll
      for (int k = 32; k >= 1; k >>= 1) P = fmaxf(P, __shfl_xor(P, k, 64));
    }
    float ex = __expf(alpha - P);
    float s0 = 0.f, s1 = 0.f;
#pragma unroll
    for (int i = 0; i < 20; i += 2) {
      float e0 = __int_as_float(__builtin_amdgcn_readlane(__float_as_int(ex), i));
      float e1 = __int_as_float(__builtin_amdgcn_readlane(__float_as_int(ex), i + 1));
      s0 = fmaf(e0, ET[i], s0);
      s1 = fmaf(e1, ET[i + 1], s1);
    }
    int tf = t + 2 < 512 ? t + 2 : 511;
    float eF = emb[tf * 20 + jj];
    if (act) alpha = P + __logf(s0 + s1) + eC;
    eC = eN;
    eN = eF;
  }
  float v = act ? (alpha + end_trans[jj]) : -1e30f;
  float Pz = v;
#pragma unroll
  for (int k = 32; k >= 1; k >>= 1) Pz = fmaxf(Pz, __shfl_xor(Pz, k, 64));
  float e2 = __expf(v - Pz);
#pragma unroll
  for (int k = 32; k >= 1; k >>= 1) e2 += __shfl_xor(e2, k, 64);
  float logZ = Pz + __logf(e2);
  if (lane == 0) partials[b] = logZ - score;
}

__global__ __launch_bounds__(128) void reduce_kernel(const float* __restrict__ partials,
                                                     float* __restrict__ out) {
  const int tid = threadIdx.x;
  float v = partials[tid];
#pragma unroll
  for (int k = 32; k >= 1; k >>= 1) v += __shfl_xor(v, k, 64);
  __shared__ float tmp[2];
  if ((tid & 63) == 0) tmp[tid >> 6] = v;
  __syncthreads();
  if (tid == 0) out[0] = tmp[0] + tmp[1];
}

// ---------------------------------------------------------------------------
extern "C" void kernel_launch(void* const* d_in, const int* in_sizes, int n_in,
                              void* d_out, int out_size, void* d_ws, size_t ws_size,
                              hipStream_t stream) {
  const int* x = (const int*)d_in[0];
  const int* y = (const int*)d_in[1];
  const int* pre_tags = (const int*)d_in[2];
  const int* pinyin_tags = (const int*)d_in[3];
  const float* char_emb = (const float*)d_in[5];
  const float* tag_emb = (const float*)d_in[6];
  const float* pinyin_emb = (const float*)d_in[7];
  const float* w_ih_f = (const float*)d_in[8];
  const float* w_hh_f = (const float*)d_in[9];
  const float* b_ih_f = (const float*)d_in[10];
  const float* b_hh_f = (const float*)d_in[11];
  const float* w_ih_b = (const float*)d_in[12];
  const float* w_hh_b = (const float*)d_in[13];
  const float* b_ih_b = (const float*)d_in[14];
  const float* b_hh_b = (const float*)d_in[15];
  const float* w_out = (const float*)d_in[16];
  const float* b_out = (const float*)d_in[17];
  const float* start_trans = (const float*)d_in[18];
  const float* end_trans = (const float*)d_in[19];
  const float* trans = (const float*)d_in[20];

  char* ws = (char*)d_ws;
  __hip_bfloat16* char_proj = (__hip_bfloat16*)(ws);            // 10002*2048*2 = 40968192
  __hip_bfloat16* pin_proj = (__hip_bfloat16*)(ws + 40968192);  // 500*2048*2  = 2048000
  __hip_bfloat16* tag_proj = (__hip_bfloat16*)(ws + 43016192);  // 20*2048*2   = 81920
  __hip_bfloat16* h_glob = (__hip_bfloat16*)(ws + 43098112);    // 2*128*512*256*2 = 67108864
  float* em = (float*)(ws + 110206976);                         // 65536*20*4 = 5242880
  float* partials = (float*)(ws + 115449856);                   // 128*4
  // wq/wsc live inside the em region (em is written only after lstm finishes)
  unsigned int* wq = (unsigned int*)(ws + 110206976);           // 2*1024*64*4 = 524288
  float* wsc = (float*)(ws + 110206976 + 524288);               // 2048*4

  wquant_kernel<<<512, 256, 0, stream>>>(w_hh_f, w_hh_b, wq, wsc);

  proj_gemm<<<dim3(79, 8), 256, 0, stream>>>(char_emb, 10002, 300, 0, w_ih_f, w_ih_b,
                                             nullptr, nullptr, nullptr, nullptr, char_proj, 0);
  proj_gemm<<<dim3(4, 8), 256, 0, stream>>>(pinyin_emb, 500, 100, 300, w_ih_f, w_ih_b,
                                            nullptr, nullptr, nullptr, nullptr, pin_proj, 0);
  proj_gemm<<<dim3(1, 8), 256, 0, stream>>>(tag_emb, 20, 50, 400, w_ih_f, w_ih_b,
                                            b_ih_f, b_hh_f, b_ih_b, b_hh_b, tag_proj, 1);

  const int lstm_lds = 16896;  // 16384 hist + 512 hbuf
  hipFuncSetAttribute((const void*)lstm_kernel, hipFuncAttributeMaxDynamicSharedMemorySize,
                      lstm_lds);
  lstm_kernel<<<256, 1024, lstm_lds, stream>>>(wq, wsc, x, pinyin_tags, pre_tags,
                                               (const char*)char_proj, (const char*)pin_proj,
                                               (const char*)tag_proj, h_glob);

  emis_kernel<<<1024, 256, 0, stream>>>(h_glob, w_out, b_out, em);
  crf_kernel<<<128, 64, 0, stream>>>(em, y, start_trans, end_trans, trans, partials);
  reduce_kernel<<<1, 128, 0, stream>>>(partials, (float*)d_out);
}

// Round 5
// 966.531 us; speedup vs baseline: 3.1562x; 1.3301x over previous
//
#include <hip/hip_runtime.h>
#include <hip/hip_bf16.h>

typedef __attribute__((ext_vector_type(8))) short short8;
typedef __attribute__((ext_vector_type(4))) float float4v;
typedef __attribute__((ext_vector_type(4))) int int4v;

__device__ __forceinline__ float sigmoidf_(float x) {
  return __fdividef(1.f, 1.f + __expf(-x));
}
__device__ __forceinline__ float tanhf_(float x) {
  float e = __expf(2.f * x);
  return 1.f - __fdividef(2.f, e + 1.f);
}
__device__ __forceinline__ float bflo(unsigned int v) {
  return __uint_as_float(v << 16);
}
__device__ __forceinline__ float bfhi(unsigned int v) {
  return __uint_as_float(v & 0xffff0000u);
}
// barrier that waits only LDS counts (h ordering) -- skips the vmcnt(0) drain
__device__ __forceinline__ void barrier_lgkm() {
  asm volatile("s_waitcnt lgkmcnt(0)\n\ts_barrier" ::: "memory");
}

__device__ __forceinline__ unsigned int pack4_(float4 v, float inv) {
  int b0 = (int)rintf(v.x * inv), b1 = (int)rintf(v.y * inv);
  int b2 = (int)rintf(v.z * inv), b3 = (int)rintf(v.w * inv);
  return (unsigned int)((b0 & 0xff) | ((b1 & 0xff) << 8) | ((b2 & 0xff) << 16) |
                        ((b3 & 0xff) << 24));
}

// select component rr (runtime 0..3) from an int4v with literal indices only
__device__ __forceinline__ int sel4_(int4v v, int rr) {
  int a = (rr & 1) ? v[1] : v[0];
  int b = (rr & 1) ? v[3] : v[2];
  return (rr & 2) ? b : a;
}

// ---------------------------------------------------------------------------
// Kernel Q: one-time int8 weight quantization. One wave per gate row.
// wq layout: row-major, 64 u32 (256 i8 along K) per gate-row.
// ---------------------------------------------------------------------------
__global__ __launch_bounds__(256) void wquant_kernel(
    const float* __restrict__ whh_f, const float* __restrict__ whh_b,
    unsigned int* __restrict__ wq, float* __restrict__ wsc) {
  const int wave_g = blockIdx.x * 4 + (threadIdx.x >> 6);
  const int lane = threadIdx.x & 63;
  const int dir = wave_g >> 10, row = wave_g & 1023;
  const float* __restrict__ src = (dir ? whh_b : whh_f) + (size_t)row * 256;
  float4 v = ((const float4*)src)[lane];
  float mx = fmaxf(fmaxf(fabsf(v.x), fabsf(v.y)), fmaxf(fabsf(v.z), fabsf(v.w)));
#pragma unroll
  for (int k = 32; k >= 1; k >>= 1) mx = fmaxf(mx, __shfl_xor(mx, k, 64));
  float inv = (mx > 0.f) ? __fdividef(127.f, mx) : 0.f;
  wq[(size_t)wave_g * 64 + lane] = pack4_(v, inv);
  if (lane == 0) wsc[wave_g] = (mx > 0.f) ? (mx / (127.f * 127.f)) : 0.f;
}

// ---------------------------------------------------------------------------
// Kernel A: projected embedding tables. M-tile 128.
// Stored at out[m*2048 + dir*1024 + u*4 + gate]  ([row][dir][unit][i,f,g,o]).
// ---------------------------------------------------------------------------
__global__ __launch_bounds__(256) void proj_gemm(
    const float* __restrict__ A, int rowsA, int Kdim, int col_off,
    const float* __restrict__ wf, const float* __restrict__ wb,
    const float* __restrict__ bf1, const float* __restrict__ bf2,
    const float* __restrict__ bb1, const float* __restrict__ bb2,
    __hip_bfloat16* __restrict__ out, int add_bias) {
  __shared__ __align__(16) __hip_bfloat16 As[128][40];
  __shared__ __align__(16) __hip_bfloat16 Bs[256][40];
  const int tid = threadIdx.x;
  const int m0 = blockIdx.x * 128, n0 = blockIdx.y * 256;
  const int lane = tid & 63, wave = tid >> 6;
  const int quad = lane >> 4, lm = lane & 15;
  float4v acc[2][16] = {};
  const int ksteps = (Kdim + 31) >> 5;
  const int r2 = tid >> 1, cbase = (tid & 1) << 4;
  const int rb = tid >> 4, cb = (tid & 15) * 2;
  for (int ks = 0; ks < ksteps; ++ks) {
    const int k0 = ks << 5;
#pragma unroll
    for (int e2 = 0; e2 < 8; ++e2) {
      int kk = k0 + cbase + 2 * e2;
      float b0 = 0.f, b1 = 0.f;
      if (m0 + r2 < rowsA && kk < Kdim) {
        float2 v = *(const float2*)(A + (size_t)(m0 + r2) * Kdim + kk);
        b0 = v.x;
        b1 = v.y;
      }
      As[r2][cbase + 2 * e2] = __float2bfloat16(b0);
      As[r2][cbase + 2 * e2 + 1] = __float2bfloat16(b1);
    }
#pragma unroll
    for (int j = 0; j < 16; ++j) {
      int n = n0 + rb + 16 * j;
      const float* __restrict__ wrow =
          (n < 1024) ? (wf + n * 450 + col_off) : (wb + (n - 1024) * 450 + col_off);
      int kk = k0 + cb;
      float b0 = 0.f, b1 = 0.f;
      if (kk < Kdim) {
        float2 v = *(const float2*)(wrow + kk);
        b0 = v.x;
        b1 = v.y;
      }
      Bs[rb + 16 * j][cb] = __float2bfloat16(b0);
      Bs[rb + 16 * j][cb + 1] = __float2bfloat16(b1);
    }
    __syncthreads();
    short8 af0 = *(const short8*)(&As[wave * 32 + lm][quad * 8]);
    short8 af1 = *(const short8*)(&As[wave * 32 + 16 + lm][quad * 8]);
#pragma unroll
    for (int t = 0; t < 16; ++t) {
      short8 bf = *(const short8*)(&Bs[t * 16 + lm][quad * 8]);
      acc[0][t] = __builtin_amdgcn_mfma_f32_16x16x32_bf16(af0, bf, acc[0][t], 0, 0, 0);
      acc[1][t] = __builtin_amdgcn_mfma_f32_16x16x32_bf16(af1, bf, acc[1][t], 0, 0, 0);
    }
    __syncthreads();
  }
#pragma unroll
  for (int mg = 0; mg < 2; ++mg) {
#pragma unroll
    for (int t = 0; t < 16; ++t) {
#pragma unroll
      for (int rr = 0; rr < 4; ++rr) {
        int m = m0 + wave * 32 + mg * 16 + quad * 4 + rr;
        int col = n0 + t * 16 + lm;
        if (m < rowsA) {
          float v = acc[mg][t][rr];
          if (add_bias)
            v += (col < 1024) ? (bf1[col] + bf2[col]) : (bb1[col - 1024] + bb2[col - 1024]);
          int dir = col >> 10, rq = col & 1023;
          int gate = rq >> 8, u = rq & 255;
          out[m * 2048 + dir * 1024 + u * 4 + gate] = __float2bfloat16(v);
        }
      }
    }
  }
}

// ---------------------------------------------------------------------------
// Kernel B (R18): BiLSTM recurrence = R15's proven shell (256 blocks = 1
// chain/block, 512 threads, scalar idx prefetch, hist ring + 16-step flush)
// with the dot4 core replaced by R16's proven-correct int8 MFMA core.
//
// Why: 4 rounds showed the dot4 path's VALU-operand register war is
// unwinnable (allocator spills weight arrays every time; each spilled dword
// costs 1 VALU move per step). MFMA reads AGPRs NATIVELY -- R16 held 128
// fragment dwords resident (VGPR=120, no spill) with zero move cost. R16's
// 3.7x regression was gather concentration (16 blocks x 98KB/step random L3
// = MLP-bound), NOT the matrix math. Here: 256 blocks keep gathers at the
// R13-proven 6KB/CU/step.
//
// Core: D[1024 gate-rows, 16 cols] = Wq(i8) x B(i8) via 256 x
// mfma_i32_16x16x64_i8 per step (32/wave). B cols = the chain's h
// REPLICATED (all 16 cols read the same LDS bytes -- broadcast, free), so
// every lane holds a valid D copy. Lane (quad, lm) decodes (mt,rr)=lm>>1 ->
// owns unit = w*32+mt*16+quad*4+rr: gate math is 1 unit/lane (R15 did ~8x
// more VALU/wave). Integer MFMA accumulation is exact == dot4 numerics.
// MFMA pipe floor: 64 mfma/SIMD x ~20cy = 1280 cy/step.
// ---------------------------------------------------------------------------
__global__ __launch_bounds__(512, 2) void lstm_kernel(
    const unsigned int* __restrict__ wq, const float* __restrict__ wsc,
    const int* __restrict__ x, const int* __restrict__ ptags, const int* __restrict__ gtags,
    const char* __restrict__ char_proj, const char* __restrict__ pin_proj,
    const char* __restrict__ tag_proj, __hip_bfloat16* __restrict__ h_out) {
  extern __shared__ __align__(16) char smem[];
  __hip_bfloat16* hist = (__hip_bfloat16*)smem;  // 32*256*2 = 16384
  char* hqb = smem + 16384;                      // 2 x 272 (256 i8 h + pad)

  const int tid = threadIdx.x;
  const int w = tid >> 6, lane = tid & 63;
  const int quad = lane >> 4, lm = lane & 15;
  const int sel = lm >> 1;               // 0..7
  const int mt = sel >> 2, rr = sel & 3; // runtime, used with literal idx only
  const int unit = w * 32 + mt * 16 + quad * 4 + rr;
  const int chain = blockIdx.x;
  const int dir = chain >> 7;
  const int b = chain & 127;
  const int boff = b * 512;

  if (tid < 34) ((uint4*)hqb)[tid] = make_uint4(0, 0, 0, 0);

  // weight fragments (MFMA A): Wf[g][m][kt], row = g*256 + w*32 + m*16 + lm,
  // dwords kt*16 + quad*4 .. +3  (layout validated end-to-end by R16's pass)
  const unsigned int* __restrict__ wqd = wq + (size_t)dir * 65536;
  int4v Wf[4][2][4];
#pragma unroll
  for (int g = 0; g < 4; ++g)
#pragma unroll
    for (int m = 0; m < 2; ++m) {
      const int row = g * 256 + w * 32 + m * 16 + lm;
#pragma unroll
      for (int kt = 0; kt < 4; ++kt)
        Wf[g][m][kt] = *(const int4v*)(wqd + row * 64 + kt * 16 + quad * 4);
    }
  float sc4[4];
#pragma unroll
  for (int g = 0; g < 4; ++g) sc4[g] = wsc[dir * 1024 + g * 256 + unit];
  __syncthreads();

  const int pre_off = dir * 2048 + unit * 8;  // byte offset into proj rows
  float cst = 0.f;

  // prefetch rotation: indices 2 steps ahead (scalar), gathers 1 step ahead
  int t_cur = dir ? 511 : 0;
  int t_nxt = dir ? 510 : 1;
  int xc = x[boff + t_cur], pc_i = ptags[boff + t_cur], gc_i = gtags[boff + t_cur];
  uint2 vc = *(const uint2*)(char_proj + (size_t)xc * 4096 + pre_off);
  uint2 vp = *(const uint2*)(pin_proj + (size_t)pc_i * 4096 + pre_off);
  uint2 vg = *(const uint2*)(tag_proj + (size_t)gc_i * 4096 + pre_off);
  int xn = x[boff + t_nxt], pn = ptags[boff + t_nxt], gn = gtags[boff + t_nxt];

  for (int s = 0; s < 512; ++s) {
    const int cur = s & 1, nxt = cur ^ 1;
    const uint2 cv = vc, pv = vp, gv = vg;
    const int t_fut = dir ? (t_nxt > 0 ? t_nxt - 1 : 0) : (t_nxt < 511 ? t_nxt + 1 : 511);
    vc = *(const uint2*)(char_proj + (size_t)xn * 4096 + pre_off);
    vp = *(const uint2*)(pin_proj + (size_t)pn * 4096 + pre_off);
    vg = *(const uint2*)(tag_proj + (size_t)gn * 4096 + pre_off);
    xn = x[boff + t_fut];
    pn = ptags[boff + t_fut];
    gn = gtags[boff + t_fut];

    // MFMA: D[row, col] with all 16 B-cols = same h (broadcast LDS reads)
    int4v acc[4][2] = {};
    const char* hqc = hqb + cur * 272;
#pragma unroll
    for (int kt = 0; kt < 4; ++kt) {
      int4v Bv = *(const int4v*)(hqc + kt * 64 + quad * 16);
#pragma unroll
      for (int g = 0; g < 4; ++g)
#pragma unroll
        for (int m = 0; m < 2; ++m)
          acc[g][m] = __builtin_amdgcn_mfma_i32_16x16x64_i8(Wf[g][m][kt], Bv, acc[g][m], 0, 0, 0);
    }

    // gate math: this lane's unit; acc component picked by (mt, rr)
    int ai = mt ? sel4_(acc[0][1], rr) : sel4_(acc[0][0], rr);
    int af = mt ? sel4_(acc[1][1], rr) : sel4_(acc[1][0], rr);
    int ag = mt ? sel4_(acc[2][1], rr) : sel4_(acc[2][0], rr);
    int ao = mt ? sel4_(acc[3][1], rr) : sel4_(acc[3][0], rr);
    float gi = bflo(cv.x) + bflo(pv.x) + bflo(gv.x) + (float)ai * sc4[0];
    float gf = bfhi(cv.x) + bfhi(pv.x) + bfhi(gv.x) + (float)af * sc4[1];
    float gg = bflo(cv.y) + bflo(pv.y) + bflo(gv.y) + (float)ag * sc4[2];
    float go = bfhi(cv.y) + bfhi(pv.y) + bfhi(gv.y) + (float)ao * sc4[3];
    cst = sigmoidf_(gf) * cst + sigmoidf_(gi) * tanhf_(gg);
    float hval = sigmoidf_(go) * tanhf_(cst);
    if (!(lm & 1)) {  // even lm lanes cover all 256 units exactly once
      ((signed char*)hqb)[nxt * 272 + unit] = (signed char)(int)rintf(hval * 127.f);
      hist[(s & 31) * 256 + unit] = __float2bfloat16(hval);
    }
    barrier_lgkm();
    if ((s & 15) == 15) {
      const int slotBase = (s & 31) & ~15;
      const int sBase = s - 15;
      const int row = tid >> 5;  // 512 threads: 16 steps x 32 uint4
      const int col16 = tid & 31;
      uint4 v = *(const uint4*)((const char*)hist + (slotBase + row) * 512 + col16 * 16);
      int step_r = sBase + row;
      int t_r = dir ? (511 - step_r) : step_r;
      *(uint4*)((char*)h_out + ((size_t)(chain * 512 + t_r) * 256) * 2 + col16 * 16) = v;
    }
    t_cur = t_nxt;
    t_nxt = t_fut;
  }
}

// ---------------------------------------------------------------------------
// Kernel C: emissions GEMM. em[b*512+t][k] = Hcat[n]·w_out[k] + b_out[k]
// ---------------------------------------------------------------------------
__global__ __launch_bounds__(256) void emis_kernel(
    const __hip_bfloat16* __restrict__ h_glob, const float* __restrict__ w_out,
    const float* __restrict__ b_out, float* __restrict__ em) {
  __shared__ __align__(16) __hip_bfloat16 As[64][40];
  __shared__ __align__(16) __hip_bfloat16 Bs[32][40];
  const int tid = threadIdx.x;
  const int n0 = blockIdx.x * 64;
  const int lane = tid & 63, wave = tid >> 6, quad = lane >> 4, lm = lane & 15;
  float4v acc[2] = {};
  const int r = tid >> 2, c0 = (tid & 3) << 3;
  const int rb = tid >> 3, cb = (tid & 7) << 2;
  for (int ks = 0; ks < 16; ++ks) {
    const int j0 = ks * 32;
    const int dirk = j0 >> 8, jin = j0 & 255;
    const int n = n0 + r, bb = n >> 9, tt = n & 511;
    const uint4* src =
        (const uint4*)(h_glob + ((size_t)(dirk * 128 + bb) * 512 + tt) * 256 + jin + c0);
    *(uint4*)(&As[r][c0]) = *src;
#pragma unroll
    for (int e = 0; e < 4; ++e) {
      float v = (rb < 20) ? w_out[rb * 512 + j0 + cb + e] : 0.f;
      Bs[rb][cb + e] = __float2bfloat16(v);
    }
    __syncthreads();
    short8 af = *(const short8*)(&As[wave * 16 + lm][quad * 8]);
#pragma unroll
    for (int t2 = 0; t2 < 2; ++t2) {
      short8 bf = *(const short8*)(&Bs[t2 * 16 + lm][quad * 8]);
      acc[t2] = __builtin_amdgcn_mfma_f32_16x16x32_bf16(af, bf, acc[t2], 0, 0, 0);
    }
    __syncthreads();
  }
#pragma unroll
  for (int t2 = 0; t2 < 2; ++t2) {
#pragma unroll
    for (int rr = 0; rr < 4; ++rr) {
      int col = t2 * 16 + lm;
      if (col < 20) {
        int n = n0 + wave * 16 + quad * 4 + rr;
        em[(size_t)n * 20 + col] = acc[t2][rr] + b_out[col];
      }
    }
  }
}

// ---------------------------------------------------------------------------
// Kernel D: CRF forward NLL. 1 wave per batch element, readlane broadcast.
// ---------------------------------------------------------------------------
__global__ __launch_bounds__(64) void crf_kernel(
    const float* __restrict__ em, const int* __restrict__ y,
    const float* __restrict__ start_trans, const float* __restrict__ end_trans,
    const float* __restrict__ trans, float* __restrict__ partials) {
  const int b = blockIdx.x;
  const int lane = threadIdx.x;
  const int jj = lane < 20 ? lane : 19;
  const bool act = lane < 20;
  const float* __restrict__ emb = em + (size_t)b * 512 * 20;
  const int* __restrict__ yb = y + b * 512;

  float s_part = 0.f;
#pragma unroll
  for (int i = 0; i < 8; ++i) {
    int t = lane + 64 * i;
    int yc = yb[t];
    float v = emb[t * 20 + yc];
    v += (t == 0) ? start_trans[yc] : trans[yb[t - 1] * 20 + yc];
    s_part += v;
  }
#pragma unroll
  for (int k = 32; k >= 1; k >>= 1) s_part += __shfl_xor(s_part, k, 64);
  float score = s_part + end_trans[yb[511]];

  float ET[20];
#pragma unroll
  for (int i = 0; i < 20; ++i) ET[i] = __expf(trans[i * 20 + jj]);
  float alpha = act ? (start_trans[jj] + emb[jj]) : -1e30f;
  float P = alpha;
#pragma unroll
  for (int k = 32; k >= 1; k >>= 1) P = fmaxf(P, __shfl_xor(P, k, 64));

  float eC = emb[1 * 20 + jj];
  float eN = emb[2 * 20 + jj];
  for (int t = 1; t < 512; ++t) {
    if ((t & 15) == 0) {
      P = alpha;
#pragma unroll
      for (int k = 32; k >= 1; k >>= 1) P = fmaxf(P, __shfl_xor(P, k, 64));
    }
    float ex = __expf(alpha - P);
    float s0 = 0.f, s1 = 0.f;
#pragma unroll
    for (int i = 0; i < 20; i += 2) {
      float e0 = __int_as_float(__builtin_amdgcn_readlane(__float_as_int(ex), i));
      float e1 = __int_as_float(__builtin_amdgcn_readlane(__float_as_int(ex), i + 1));
      s0 = fmaf(e0, ET[i], s0);
      s1 = fmaf(e1, ET[i + 1], s1);
    }
    int tf = t + 2 < 512 ? t + 2 : 511;
    float eF = emb[tf * 20 + jj];
    if (act) alpha = P + __logf(s0 + s1) + eC;
    eC = eN;
    eN = eF;
  }
  float v = act ? (alpha + end_trans[jj]) : -1e30f;
  float Pz = v;
#pragma unroll
  for (int k = 32; k >= 1; k >>= 1) Pz = fmaxf(Pz, __shfl_xor(Pz, k, 64));
  float e2 = __expf(v - Pz);
#pragma unroll
  for (int k = 32; k >= 1; k >>= 1) e2 += __shfl_xor(e2, k, 64);
  float logZ = Pz + __logf(e2);
  if (lane == 0) partials[b] = logZ - score;
}

__global__ __launch_bounds__(128) void reduce_kernel(const float* __restrict__ partials,
                                                     float* __restrict__ out) {
  const int tid = threadIdx.x;
  float v = partials[tid];
#pragma unroll
  for (int k = 32; k >= 1; k >>= 1) v += __shfl_xor(v, k, 64);
  __shared__ float tmp[2];
  if ((tid & 63) == 0) tmp[tid >> 6] = v;
  __syncthreads();
  if (tid == 0) out[0] = tmp[0] + tmp[1];
}

// ---------------------------------------------------------------------------
extern "C" void kernel_launch(void* const* d_in, const int* in_sizes, int n_in,
                              void* d_out, int out_size, void* d_ws, size_t ws_size,
                              hipStream_t stream) {
  const int* x = (const int*)d_in[0];
  const int* y = (const int*)d_in[1];
  const int* pre_tags = (const int*)d_in[2];
  const int* pinyin_tags = (const int*)d_in[3];
  const float* char_emb = (const float*)d_in[5];
  const float* tag_emb = (const float*)d_in[6];
  const float* pinyin_emb = (const float*)d_in[7];
  const float* w_ih_f = (const float*)d_in[8];
  const float* w_hh_f = (const float*)d_in[9];
  const float* b_ih_f = (const float*)d_in[10];
  const float* b_hh_f = (const float*)d_in[11];
  const float* w_ih_b = (const float*)d_in[12];
  const float* w_hh_b = (const float*)d_in[13];
  const float* b_ih_b = (const float*)d_in[14];
  const float* b_hh_b = (const float*)d_in[15];
  const float* w_out = (const float*)d_in[16];
  const float* b_out = (const float*)d_in[17];
  const float* start_trans = (const float*)d_in[18];
  const float* end_trans = (const float*)d_in[19];
  const float* trans = (const float*)d_in[20];

  char* ws = (char*)d_ws;
  __hip_bfloat16* char_proj = (__hip_bfloat16*)(ws);            // 10002*2048*2 = 40968192
  __hip_bfloat16* pin_proj = (__hip_bfloat16*)(ws + 40968192);  // 500*2048*2  = 2048000
  __hip_bfloat16* tag_proj = (__hip_bfloat16*)(ws + 43016192);  // 20*2048*2   = 81920
  __hip_bfloat16* h_glob = (__hip_bfloat16*)(ws + 43098112);    // 2*128*512*256*2 = 67108864
  float* em = (float*)(ws + 110206976);                         // 65536*20*4 = 5242880
  float* partials = (float*)(ws + 115449856);                   // 128*4
  // wq/wsc live inside the em region (em is written only after lstm finishes)
  unsigned int* wq = (unsigned int*)(ws + 110206976);           // 2*1024*64*4 = 524288
  float* wsc = (float*)(ws + 110206976 + 524288);               // 2048*4

  wquant_kernel<<<512, 256, 0, stream>>>(w_hh_f, w_hh_b, wq, wsc);

  proj_gemm<<<dim3(79, 8), 256, 0, stream>>>(char_emb, 10002, 300, 0, w_ih_f, w_ih_b,
                                             nullptr, nullptr, nullptr, nullptr, char_proj, 0);
  proj_gemm<<<dim3(4, 8), 256, 0, stream>>>(pinyin_emb, 500, 100, 300, w_ih_f, w_ih_b,
                                            nullptr, nullptr, nullptr, nullptr, pin_proj, 0);
  proj_gemm<<<dim3(1, 8), 256, 0, stream>>>(tag_emb, 20, 50, 400, w_ih_f, w_ih_b,
                                            b_ih_f, b_hh_f, b_ih_b, b_hh_b, tag_proj, 1);

  const int lstm_lds = 16928;  // 16384 hist + 544 hq double buffer
  hipFuncSetAttribute((const void*)lstm_kernel, hipFuncAttributeMaxDynamicSharedMemorySize,
                      lstm_lds);
  lstm_kernel<<<256, 512, lstm_lds, stream>>>(wq, wsc, x, pinyin_tags, pre_tags,
                                              (const char*)char_proj, (const char*)pin_proj,
                                              (const char*)tag_proj, h_glob);

  emis_kernel<<<1024, 256, 0, stream>>>(h_glob, w_out, b_out, em);
  crf_kernel<<<128, 64, 0, stream>>>(em, y, start_trans, end_trans, trans, partials);
  reduce_kernel<<<1, 128, 0, stream>>>(partials, (float*)d_out);
}

// Round 6
// 959.796 us; speedup vs baseline: 3.1784x; 1.0070x over previous
//
#include <hip/hip_runtime.h>
#include <hip/hip_bf16.h>

typedef __attribute__((ext_vector_type(8))) short short8;
typedef __attribute__((ext_vector_type(4))) float float4v;
typedef __attribute__((ext_vector_type(4))) int int4v;

__device__ __forceinline__ float sigmoidf_(float x) {
  return __fdividef(1.f, 1.f + __expf(-x));
}
__device__ __forceinline__ float tanhf_(float x) {
  float e = __expf(2.f * x);
  return 1.f - __fdividef(2.f, e + 1.f);
}
__device__ __forceinline__ float bflo(unsigned int v) {
  return __uint_as_float(v << 16);
}
__device__ __forceinline__ float bfhi(unsigned int v) {
  return __uint_as_float(v & 0xffff0000u);
}
// barrier that waits only LDS counts (h ordering) -- skips the vmcnt(0) drain
__device__ __forceinline__ void barrier_lgkm() {
  asm volatile("s_waitcnt lgkmcnt(0)\n\ts_barrier" ::: "memory");
}

__device__ __forceinline__ unsigned int pack4_(float4 v, float inv) {
  int b0 = (int)rintf(v.x * inv), b1 = (int)rintf(v.y * inv);
  int b2 = (int)rintf(v.z * inv), b3 = (int)rintf(v.w * inv);
  return (unsigned int)((b0 & 0xff) | ((b1 & 0xff) << 8) | ((b2 & 0xff) << 16) |
                        ((b3 & 0xff) << 24));
}

// select component rr (runtime 0..3) from an int4v with literal indices only
__device__ __forceinline__ int sel4_(int4v v, int rr) {
  int a = (rr & 1) ? v[1] : v[0];
  int b = (rr & 1) ? v[3] : v[2];
  return (rr & 2) ? b : a;
}

// ---------------------------------------------------------------------------
// Kernel Q: one-time int8 weight quantization. One wave per gate row.
// wq layout: row-major, 64 u32 (256 i8 along K) per gate-row.
// ---------------------------------------------------------------------------
__global__ __launch_bounds__(256) void wquant_kernel(
    const float* __restrict__ whh_f, const float* __restrict__ whh_b,
    unsigned int* __restrict__ wq, float* __restrict__ wsc) {
  const int wave_g = blockIdx.x * 4 + (threadIdx.x >> 6);
  const int lane = threadIdx.x & 63;
  const int dir = wave_g >> 10, row = wave_g & 1023;
  const float* __restrict__ src = (dir ? whh_b : whh_f) + (size_t)row * 256;
  float4 v = ((const float4*)src)[lane];
  float mx = fmaxf(fmaxf(fabsf(v.x), fabsf(v.y)), fmaxf(fabsf(v.z), fabsf(v.w)));
#pragma unroll
  for (int k = 32; k >= 1; k >>= 1) mx = fmaxf(mx, __shfl_xor(mx, k, 64));
  float inv = (mx > 0.f) ? __fdividef(127.f, mx) : 0.f;
  wq[(size_t)wave_g * 64 + lane] = pack4_(v, inv);
  if (lane == 0) wsc[wave_g] = (mx > 0.f) ? (mx / (127.f * 127.f)) : 0.f;
}

// ---------------------------------------------------------------------------
// Kernel A: projected embedding tables. M-tile 128.
// Stored at out[m*2048 + dir*1024 + u*4 + gate]  ([row][dir][unit][i,f,g,o]).
// ---------------------------------------------------------------------------
__global__ __launch_bounds__(256) void proj_gemm(
    const float* __restrict__ A, int rowsA, int Kdim, int col_off,
    const float* __restrict__ wf, const float* __restrict__ wb,
    const float* __restrict__ bf1, const float* __restrict__ bf2,
    const float* __restrict__ bb1, const float* __restrict__ bb2,
    __hip_bfloat16* __restrict__ out, int add_bias) {
  __shared__ __align__(16) __hip_bfloat16 As[128][40];
  __shared__ __align__(16) __hip_bfloat16 Bs[256][40];
  const int tid = threadIdx.x;
  const int m0 = blockIdx.x * 128, n0 = blockIdx.y * 256;
  const int lane = tid & 63, wave = tid >> 6;
  const int quad = lane >> 4, lm = lane & 15;
  float4v acc[2][16] = {};
  const int ksteps = (Kdim + 31) >> 5;
  const int r2 = tid >> 1, cbase = (tid & 1) << 4;
  const int rb = tid >> 4, cb = (tid & 15) * 2;
  for (int ks = 0; ks < ksteps; ++ks) {
    const int k0 = ks << 5;
#pragma unroll
    for (int e2 = 0; e2 < 8; ++e2) {
      int kk = k0 + cbase + 2 * e2;
      float b0 = 0.f, b1 = 0.f;
      if (m0 + r2 < rowsA && kk < Kdim) {
        float2 v = *(const float2*)(A + (size_t)(m0 + r2) * Kdim + kk);
        b0 = v.x;
        b1 = v.y;
      }
      As[r2][cbase + 2 * e2] = __float2bfloat16(b0);
      As[r2][cbase + 2 * e2 + 1] = __float2bfloat16(b1);
    }
#pragma unroll
    for (int j = 0; j < 16; ++j) {
      int n = n0 + rb + 16 * j;
      const float* __restrict__ wrow =
          (n < 1024) ? (wf + n * 450 + col_off) : (wb + (n - 1024) * 450 + col_off);
      int kk = k0 + cb;
      float b0 = 0.f, b1 = 0.f;
      if (kk < Kdim) {
        float2 v = *(const float2*)(wrow + kk);
        b0 = v.x;
        b1 = v.y;
      }
      Bs[rb + 16 * j][cb] = __float2bfloat16(b0);
      Bs[rb + 16 * j][cb + 1] = __float2bfloat16(b1);
    }
    __syncthreads();
    short8 af0 = *(const short8*)(&As[wave * 32 + lm][quad * 8]);
    short8 af1 = *(const short8*)(&As[wave * 32 + 16 + lm][quad * 8]);
#pragma unroll
    for (int t = 0; t < 16; ++t) {
      short8 bf = *(const short8*)(&Bs[t * 16 + lm][quad * 8]);
      acc[0][t] = __builtin_amdgcn_mfma_f32_16x16x32_bf16(af0, bf, acc[0][t], 0, 0, 0);
      acc[1][t] = __builtin_amdgcn_mfma_f32_16x16x32_bf16(af1, bf, acc[1][t], 0, 0, 0);
    }
    __syncthreads();
  }
#pragma unroll
  for (int mg = 0; mg < 2; ++mg) {
#pragma unroll
    for (int t = 0; t < 16; ++t) {
#pragma unroll
      for (int rr = 0; rr < 4; ++rr) {
        int m = m0 + wave * 32 + mg * 16 + quad * 4 + rr;
        int col = n0 + t * 16 + lm;
        if (m < rowsA) {
          float v = acc[mg][t][rr];
          if (add_bias)
            v += (col < 1024) ? (bf1[col] + bf2[col]) : (bb1[col - 1024] + bb2[col - 1024]);
          int dir = col >> 10, rq = col & 1023;
          int gate = rq >> 8, u = rq & 255;
          out[m * 2048 + dir * 1024 + u * 4 + gate] = __float2bfloat16(v);
        }
      }
    }
  }
}

// ---------------------------------------------------------------------------
// Kernel P: pre-sum pinyin + tag projections: pg[p*20+g] = pin[p] + tag[g].
// 10000 rows x 2048 bf16. One block per row, 256 threads x 8 elems.
// Removes one gather + its unpack/add chain from every lstm step.
// ---------------------------------------------------------------------------
__global__ __launch_bounds__(256) void pgsum_kernel(
    const __hip_bfloat16* __restrict__ pin, const __hip_bfloat16* __restrict__ tag,
    __hip_bfloat16* __restrict__ pg) {
  const int r = blockIdx.x;
  const int p = r / 20, g = r - p * 20;
  const int i = threadIdx.x;  // 256 threads x 8 bf16 = 2048
  const short8 va = *(const short8*)(pin + (size_t)p * 2048 + i * 8);
  const short8 vb = *(const short8*)(tag + (size_t)g * 2048 + i * 8);
  short8 vo;
#pragma unroll
  for (int j = 0; j < 8; ++j) {
    float a = __uint_as_float(((unsigned)(unsigned short)va[j]) << 16);
    float b = __uint_as_float(((unsigned)(unsigned short)vb[j]) << 16);
    __hip_bfloat16 o = __float2bfloat16(a + b);
    vo[j] = *(short*)&o;
  }
  *(short8*)(pg + (size_t)r * 2048 + i * 8) = vo;
}

// ---------------------------------------------------------------------------
// Kernel B (R19): R18's MFMA recurrence with the step loop ROTATED: the Bv
// ds_reads for step s+1 issue immediately after the barrier of step s, so
// LDS latency (~150cy) hides under hist-write/prefetch/loop tail instead of
// stalling the first MFMA (R18 read Bv right before the MFMA block -- full
// latency exposed every step; step was 2919cy vs 1306 MFMA + 557 VALU).
// hist-write moves after the barrier; flush steps (1/16) take a second
// barrier to order flush reads after all waves' hist writes.
// USE_PG: char + presummed pinyin-tag table (2 gathers instead of 3).
// ---------------------------------------------------------------------------
template <int USE_PG>
__global__ __launch_bounds__(512, 2) void lstm_kernel(
    const unsigned int* __restrict__ wq, const float* __restrict__ wsc,
    const int* __restrict__ x, const int* __restrict__ ptags, const int* __restrict__ gtags,
    const char* __restrict__ char_proj, const char* __restrict__ pin_proj,
    const char* __restrict__ tag_proj, const char* __restrict__ pg_proj,
    __hip_bfloat16* __restrict__ h_out) {
  extern __shared__ __align__(16) char smem[];
  __hip_bfloat16* hist = (__hip_bfloat16*)smem;  // 32*256*2 = 16384
  char* hqb = smem + 16384;                      // 2 x 272 (256 i8 h + pad)

  const int tid = threadIdx.x;
  const int w = tid >> 6, lane = tid & 63;
  const int quad = lane >> 4, lm = lane & 15;
  const int sel = lm >> 1;                // 0..7
  const int mt = sel >> 2, rr = sel & 3;  // runtime, used with literal idx only
  const int unit = w * 32 + mt * 16 + quad * 4 + rr;
  const int chain = blockIdx.x;
  const int dir = chain >> 7;
  const int b = chain & 127;
  const int boff = b * 512;

  if (tid < 34) ((uint4*)hqb)[tid] = make_uint4(0, 0, 0, 0);

  // weight fragments (MFMA A): Wf[g][m][kt], row = g*256 + w*32 + m*16 + lm
  const unsigned int* __restrict__ wqd = wq + (size_t)dir * 65536;
  int4v Wf[4][2][4];
#pragma unroll
  for (int g = 0; g < 4; ++g)
#pragma unroll
    for (int m = 0; m < 2; ++m) {
      const int row = g * 256 + w * 32 + m * 16 + lm;
#pragma unroll
      for (int kt = 0; kt < 4; ++kt)
        Wf[g][m][kt] = *(const int4v*)(wqd + row * 64 + kt * 16 + quad * 4);
    }
  float sc4[4];
#pragma unroll
  for (int g = 0; g < 4; ++g) sc4[g] = wsc[dir * 1024 + g * 256 + unit];
  __syncthreads();

  const int pre_off = dir * 2048 + unit * 8;  // byte offset into proj rows
  float cst = 0.f;

  // prefetch rotation: indices 2 steps ahead (scalar), gathers 1 step ahead
  int t_cur = dir ? 511 : 0;
  int t_nxt = dir ? 510 : 1;
  uint2 vc, vp, vg;
  int xn, pgn, pn, gn;
  {
    int xc = x[boff + t_cur], pc = ptags[boff + t_cur], gc = gtags[boff + t_cur];
    vc = *(const uint2*)(char_proj + (size_t)xc * 4096 + pre_off);
    if (USE_PG) {
      vp = *(const uint2*)(pg_proj + (size_t)(pc * 20 + gc) * 4096 + pre_off);
    } else {
      vp = *(const uint2*)(pin_proj + (size_t)pc * 4096 + pre_off);
      vg = *(const uint2*)(tag_proj + (size_t)gc * 4096 + pre_off);
    }
    xn = x[boff + t_nxt];
    pn = ptags[boff + t_nxt];
    gn = gtags[boff + t_nxt];
    if (USE_PG) pgn = pn * 20 + gn;
  }

  // prologue: Bv(0) from buffer 0 (h(-1) = 0)
  int4v Bv[4];
#pragma unroll
  for (int kt = 0; kt < 4; ++kt)
    Bv[kt] = *(const int4v*)(hqb + kt * 64 + quad * 16);

  for (int s = 0; s < 512; ++s) {
    const int nxt = (s & 1) ^ 1;
    const uint2 cv = vc, pv = vp, gv = vg;
    const int t_fut = dir ? (t_nxt > 0 ? t_nxt - 1 : 0) : (t_nxt < 511 ? t_nxt + 1 : 511);
    // issue next-step gathers + next-next indices (independent of MFMA)
    vc = *(const uint2*)(char_proj + (size_t)xn * 4096 + pre_off);
    if (USE_PG) {
      vp = *(const uint2*)(pg_proj + (size_t)pgn * 4096 + pre_off);
    } else {
      vp = *(const uint2*)(pin_proj + (size_t)pn * 4096 + pre_off);
      vg = *(const uint2*)(tag_proj + (size_t)gn * 4096 + pre_off);
    }
    xn = x[boff + t_fut];
    pn = ptags[boff + t_fut];
    gn = gtags[boff + t_fut];
    if (USE_PG) pgn = pn * 20 + gn;

    // MFMA with preloaded Bv (operands ~a full gate-phase old -> no lgkm stall)
    int4v acc[4][2] = {};
#pragma unroll
    for (int kt = 0; kt < 4; ++kt) {
#pragma unroll
      for (int g = 0; g < 4; ++g)
#pragma unroll
        for (int m = 0; m < 2; ++m)
          acc[g][m] = __builtin_amdgcn_mfma_i32_16x16x64_i8(Wf[g][m][kt], Bv[kt], acc[g][m], 0, 0, 0);
    }

    // gate math: this lane's unit; acc component picked by (mt, rr)
    int ai = mt ? sel4_(acc[0][1], rr) : sel4_(acc[0][0], rr);
    int af = mt ? sel4_(acc[1][1], rr) : sel4_(acc[1][0], rr);
    int ag = mt ? sel4_(acc[2][1], rr) : sel4_(acc[2][0], rr);
    int ao = mt ? sel4_(acc[3][1], rr) : sel4_(acc[3][0], rr);
    float gi, gf, gg, go;
    if (USE_PG) {
      gi = bflo(cv.x) + bflo(pv.x) + (float)ai * sc4[0];
      gf = bfhi(cv.x) + bfhi(pv.x) + (float)af * sc4[1];
      gg = bflo(cv.y) + bflo(pv.y) + (float)ag * sc4[2];
      go = bfhi(cv.y) + bfhi(pv.y) + (float)ao * sc4[3];
    } else {
      gi = bflo(cv.x) + bflo(pv.x) + bflo(gv.x) + (float)ai * sc4[0];
      gf = bfhi(cv.x) + bfhi(pv.x) + bfhi(gv.x) + (float)af * sc4[1];
      gg = bflo(cv.y) + bflo(pv.y) + bflo(gv.y) + (float)ag * sc4[2];
      go = bfhi(cv.y) + bfhi(pv.y) + bfhi(gv.y) + (float)ao * sc4[3];
    }
    cst = sigmoidf_(gf) * cst + sigmoidf_(gi) * tanhf_(gg);
    float hval = sigmoidf_(go) * tanhf_(cst);
    if (!(lm & 1)) {  // even lm lanes cover all 256 units exactly once
      ((signed char*)hqb)[nxt * 272 + unit] = (signed char)(int)rintf(hval * 127.f);
    }
    barrier_lgkm();
    // read Bv for step s+1 IMMEDIATELY (latency hides under the loop tail)
#pragma unroll
    for (int kt = 0; kt < 4; ++kt)
      Bv[kt] = *(const int4v*)(hqb + nxt * 272 + kt * 64 + quad * 16);
    // bf16 history write (post-barrier; ordered before flush by barrier below)
    if (!(lm & 1)) hist[(s & 31) * 256 + unit] = __float2bfloat16(hval);
    if ((s & 15) == 15) {
      barrier_lgkm();  // all waves' hist writes visible before flush reads
      const int slotBase = (s & 31) & ~15;
      const int sBase = s - 15;
      const int row = tid >> 5;  // 512 threads: 16 steps x 32 uint4
      const int col16 = tid & 31;
      uint4 v = *(const uint4*)((const char*)hist + (slotBase + row) * 512 + col16 * 16);
      int step_r = sBase + row;
      int t_r = dir ? (511 - step_r) : step_r;
      *(uint4*)((char*)h_out + ((size_t)(chain * 512 + t_r) * 256) * 2 + col16 * 16) = v;
    }
    t_cur = t_nxt;
    t_nxt = t_fut;
  }
}

// ---------------------------------------------------------------------------
// Kernel C: emissions GEMM. em[b*512+t][k] = Hcat[n]·w_out[k] + b_out[k]
// ---------------------------------------------------------------------------
__global__ __launch_bounds__(256) void emis_kernel(
    const __hip_bfloat16* __restrict__ h_glob, const float* __restrict__ w_out,
    const float* __restrict__ b_out, float* __restrict__ em) {
  __shared__ __align__(16) __hip_bfloat16 As[64][40];
  __shared__ __align__(16) __hip_bfloat16 Bs[32][40];
  const int tid = threadIdx.x;
  const int n0 = blockIdx.x * 64;
  const int lane = tid & 63, wave = tid >> 6, quad = lane >> 4, lm = lane & 15;
  float4v acc[2] = {};
  const int r = tid >> 2, c0 = (tid & 3) << 3;
  const int rb = tid >> 3, cb = (tid & 7) << 2;
  for (int ks = 0; ks < 16; ++ks) {
    const int j0 = ks * 32;
    const int dirk = j0 >> 8, jin = j0 & 255;
    const int n = n0 + r, bb = n >> 9, tt = n & 511;
    const uint4* src =
        (const uint4*)(h_glob + ((size_t)(dirk * 128 + bb) * 512 + tt) * 256 + jin + c0);
    *(uint4*)(&As[r][c0]) = *src;
#pragma unroll
    for (int e = 0; e < 4; ++e) {
      float v = (rb < 20) ? w_out[rb * 512 + j0 + cb + e] : 0.f;
      Bs[rb][cb + e] = __float2bfloat16(v);
    }
    __syncthreads();
    short8 af = *(const short8*)(&As[wave * 16 + lm][quad * 8]);
#pragma unroll
    for (int t2 = 0; t2 < 2; ++t2) {
      short8 bf = *(const short8*)(&Bs[t2 * 16 + lm][quad * 8]);
      acc[t2] = __builtin_amdgcn_mfma_f32_16x16x32_bf16(af, bf, acc[t2], 0, 0, 0);
    }
    __syncthreads();
  }
#pragma unroll
  for (int t2 = 0; t2 < 2; ++t2) {
#pragma unroll
    for (int rr = 0; rr < 4; ++rr) {
      int col = t2 * 16 + lm;
      if (col < 20) {
        int n = n0 + wave * 16 + quad * 4 + rr;
        em[(size_t)n * 20 + col] = acc[t2][rr] + b_out[col];
      }
    }
  }
}

// ---------------------------------------------------------------------------
// Kernel D: CRF forward NLL. 1 wave per batch element, readlane broadcast.
// ---------------------------------------------------------------------------
__global__ __launch_bounds__(64) void crf_kernel(
    const float* __restrict__ em, const int* __restrict__ y,
    const float* __restrict__ start_trans, const float* __restrict__ end_trans,
    const float* __restrict__ trans, float* __restrict__ partials) {
  const int b = blockIdx.x;
  const int lane = threadIdx.x;
  const int jj = lane < 20 ? lane : 19;
  const bool act = lane < 20;
  const float* __restrict__ emb = em + (size_t)b * 512 * 20;
  const int* __restrict__ yb = y + b * 512;

  float s_part = 0.f;
#pragma unroll
  for (int i = 0; i < 8; ++i) {
    int t = lane + 64 * i;
    int yc = yb[t];
    float v = emb[t * 20 + yc];
    v += (t == 0) ? start_trans[yc] : trans[yb[t - 1] * 20 + yc];
    s_part += v;
  }
#pragma unroll
  for (int k = 32; k >= 1; k >>= 1) s_part += __shfl_xor(s_part, k, 64);
  float score = s_part + end_trans[yb[511]];

  float ET[20];
#pragma unroll
  for (int i = 0; i < 20; ++i) ET[i] = __expf(trans[i * 20 + jj]);
  float alpha = act ? (start_trans[jj] + emb[jj]) : -1e30f;
  float P = alpha;
#pragma unroll
  for (int k = 32; k >= 1; k >>= 1) P = fmaxf(P, __shfl_xor(P, k, 64));

  float eC = emb[1 * 20 + jj];
  float eN = emb[2 * 20 + jj];
  for (int t = 1; t < 512; ++t) {
    if ((t & 15) == 0) {
      P = alpha;
#pragma unroll
      for (int k = 32; k >= 1; k >>= 1) P = fmaxf(P, __shfl_xor(P, k, 64));
    }
    float ex = __expf(alpha - P);
    float s0 = 0.f, s1 = 0.f;
#pragma unroll
    for (int i = 0; i < 20; i += 2) {
      float e0 = __int_as_float(__builtin_amdgcn_readlane(__float_as_int(ex), i));
      float e1 = __int_as_float(__builtin_amdgcn_readlane(__float_as_int(ex), i + 1));
      s0 = fmaf(e0, ET[i], s0);
      s1 = fmaf(e1, ET[i + 1], s1);
    }
    int tf = t + 2 < 512 ? t + 2 : 511;
    float eF = emb[tf * 20 + jj];
    if (act) alpha = P + __logf(s0 + s1) + eC;
    eC = eN;
    eN = eF;
  }
  float v = act ? (alpha + end_trans[jj]) : -1e30f;
  float Pz = v;
#pragma unroll
  for (int k = 32; k >= 1; k >>= 1) Pz = fmaxf(Pz, __shfl_xor(Pz, k, 64));
  float e2 = __expf(v - Pz);
#pragma unroll
  for (int k = 32; k >= 1; k >>= 1) e2 += __shfl_xor(e2, k, 64);
  float logZ = Pz + __logf(e2);
  if (lane == 0) partials[b] = logZ - score;
}

__global__ __launch_bounds__(128) void reduce_kernel(const float* __restrict__ partials,
                                                     float* __restrict__ out) {
  const int tid = threadIdx.x;
  float v = partials[tid];
#pragma unroll
  for (int k = 32; k >= 1; k >>= 1) v += __shfl_xor(v, k, 64);
  __shared__ float tmp[2];
  if ((tid & 63) == 0) tmp[tid >> 6] = v;
  __syncthreads();
  if (tid == 0) out[0] = tmp[0] + tmp[1];
}

// ---------------------------------------------------------------------------
extern "C" void kernel_launch(void* const* d_in, const int* in_sizes, int n_in,
                              void* d_out, int out_size, void* d_ws, size_t ws_size,
                              hipStream_t stream) {
  const int* x = (const int*)d_in[0];
  const int* y = (const int*)d_in[1];
  const int* pre_tags = (const int*)d_in[2];
  const int* pinyin_tags = (const int*)d_in[3];
  const float* char_emb = (const float*)d_in[5];
  const float* tag_emb = (const float*)d_in[6];
  const float* pinyin_emb = (const float*)d_in[7];
  const float* w_ih_f = (const float*)d_in[8];
  const float* w_hh_f = (const float*)d_in[9];
  const float* b_ih_f = (const float*)d_in[10];
  const float* b_hh_f = (const float*)d_in[11];
  const float* w_ih_b = (const float*)d_in[12];
  const float* w_hh_b = (const float*)d_in[13];
  const float* b_ih_b = (const float*)d_in[14];
  const float* b_hh_b = (const float*)d_in[15];
  const float* w_out = (const float*)d_in[16];
  const float* b_out = (const float*)d_in[17];
  const float* start_trans = (const float*)d_in[18];
  const float* end_trans = (const float*)d_in[19];
  const float* trans = (const float*)d_in[20];

  char* ws = (char*)d_ws;
  __hip_bfloat16* char_proj = (__hip_bfloat16*)(ws);            // 10002*2048*2 = 40968192
  __hip_bfloat16* pin_proj = (__hip_bfloat16*)(ws + 40968192);  // 500*2048*2  = 2048000
  __hip_bfloat16* tag_proj = (__hip_bfloat16*)(ws + 43016192);  // 20*2048*2   = 81920
  __hip_bfloat16* h_glob = (__hip_bfloat16*)(ws + 43098112);    // 2*128*512*256*2 = 67108864
  float* em = (float*)(ws + 110206976);                         // 65536*20*4 = 5242880
  float* partials = (float*)(ws + 115449856);                   // 128*4
  // wq/wsc live inside the em region (em is written only after lstm finishes)
  unsigned int* wq = (unsigned int*)(ws + 110206976);           // 2*1024*64*4 = 524288
  float* wsc = (float*)(ws + 110206976 + 524288);               // 2048*4
  // optional presummed pinyin+tag table (runtime-gated on ws_size)
  __hip_bfloat16* pg_proj = (__hip_bfloat16*)(ws + 115450368);  // 10000*2048*2 = 40960000
  const bool use_pg = ws_size >= (size_t)115450368 + 40960000;

  wquant_kernel<<<512, 256, 0, stream>>>(w_hh_f, w_hh_b, wq, wsc);

  proj_gemm<<<dim3(79, 8), 256, 0, stream>>>(char_emb, 10002, 300, 0, w_ih_f, w_ih_b,
                                             nullptr, nullptr, nullptr, nullptr, char_proj, 0);
  proj_gemm<<<dim3(4, 8), 256, 0, stream>>>(pinyin_emb, 500, 100, 300, w_ih_f, w_ih_b,
                                            nullptr, nullptr, nullptr, nullptr, pin_proj, 0);
  proj_gemm<<<dim3(1, 8), 256, 0, stream>>>(tag_emb, 20, 50, 400, w_ih_f, w_ih_b,
                                            b_ih_f, b_hh_f, b_ih_b, b_hh_b, tag_proj, 1);
  if (use_pg) pgsum_kernel<<<10000, 256, 0, stream>>>(pin_proj, tag_proj, pg_proj);

  const int lstm_lds = 16928;  // 16384 hist + 544 hq double buffer
  if (use_pg) {
    hipFuncSetAttribute((const void*)lstm_kernel<1>, hipFuncAttributeMaxDynamicSharedMemorySize,
                        lstm_lds);
    lstm_kernel<1><<<256, 512, lstm_lds, stream>>>(wq, wsc, x, pinyin_tags, pre_tags,
                                                   (const char*)char_proj, (const char*)pin_proj,
                                                   (const char*)tag_proj, (const char*)pg_proj,
                                                   h_glob);
  } else {
    hipFuncSetAttribute((const void*)lstm_kernel<0>, hipFuncAttributeMaxDynamicSharedMemorySize,
                        lstm_lds);
    lstm_kernel<0><<<256, 512, lstm_lds, stream>>>(wq, wsc, x, pinyin_tags, pre_tags,
                                                   (const char*)char_proj, (const char*)pin_proj,
                                                   (const char*)tag_proj, (const char*)pg_proj,
                                                   h_glob);
  }

  emis_kernel<<<1024, 256, 0, stream>>>(h_glob, w_out, b_out, em);
  crf_kernel<<<128, 64, 0, stream>>>(em, y, start_trans, end_trans, trans, partials);
  reduce_kernel<<<1, 128, 0, stream>>>(partials, (float*)d_out);
}

// Round 7
// 954.437 us; speedup vs baseline: 3.1962x; 1.0056x over previous
//
#include <hip/hip_runtime.h>
#include <hip/hip_bf16.h>

typedef __attribute__((ext_vector_type(8))) short short8;
typedef __attribute__((ext_vector_type(4))) float float4v;
typedef __attribute__((ext_vector_type(4))) int int4v;

__device__ __forceinline__ float sigmoidf_(float x) {
  return __fdividef(1.f, 1.f + __expf(-x));
}
__device__ __forceinline__ float tanhf_(float x) {
  float e = __expf(2.f * x);
  return 1.f - __fdividef(2.f, e + 1.f);
}
__device__ __forceinline__ float bflo(unsigned int v) {
  return __uint_as_float(v << 16);
}
__device__ __forceinline__ float bfhi(unsigned int v) {
  return __uint_as_float(v & 0xffff0000u);
}
// barrier that waits only LDS counts (h ordering) -- skips the vmcnt(0) drain
__device__ __forceinline__ void barrier_lgkm() {
  asm volatile("s_waitcnt lgkmcnt(0)\n\ts_barrier" ::: "memory");
}

__device__ __forceinline__ unsigned int pack4_(float4 v, float inv) {
  int b0 = (int)rintf(v.x * inv), b1 = (int)rintf(v.y * inv);
  int b2 = (int)rintf(v.z * inv), b3 = (int)rintf(v.w * inv);
  return (unsigned int)((b0 & 0xff) | ((b1 & 0xff) << 8) | ((b2 & 0xff) << 16) |
                        ((b3 & 0xff) << 24));
}

// select component rr (runtime 0..3) from an int4v with literal indices only
__device__ __forceinline__ int sel4_(int4v v, int rr) {
  int a = (rr & 1) ? v[1] : v[0];
  int b = (rr & 1) ? v[3] : v[2];
  return (rr & 2) ? b : a;
}

// ---------------------------------------------------------------------------
// Kernel Q: one-time int8 weight quantization. One wave per gate row.
// wq layout: row-major, 64 u32 (256 i8 along K) per gate-row.
// ---------------------------------------------------------------------------
__global__ __launch_bounds__(256) void wquant_kernel(
    const float* __restrict__ whh_f, const float* __restrict__ whh_b,
    unsigned int* __restrict__ wq, float* __restrict__ wsc) {
  const int wave_g = blockIdx.x * 4 + (threadIdx.x >> 6);
  const int lane = threadIdx.x & 63;
  const int dir = wave_g >> 10, row = wave_g & 1023;
  const float* __restrict__ src = (dir ? whh_b : whh_f) + (size_t)row * 256;
  float4 v = ((const float4*)src)[lane];
  float mx = fmaxf(fmaxf(fabsf(v.x), fabsf(v.y)), fmaxf(fabsf(v.z), fabsf(v.w)));
#pragma unroll
  for (int k = 32; k >= 1; k >>= 1) mx = fmaxf(mx, __shfl_xor(mx, k, 64));
  float inv = (mx > 0.f) ? __fdividef(127.f, mx) : 0.f;
  wq[(size_t)wave_g * 64 + lane] = pack4_(v, inv);
  if (lane == 0) wsc[wave_g] = (mx > 0.f) ? (mx / (127.f * 127.f)) : 0.f;
}

// ---------------------------------------------------------------------------
// Kernel A: projected embedding tables. M-tile 128.
// Stored at out[m*2048 + dir*1024 + u*4 + gate]  ([row][dir][unit][i,f,g,o]).
// ---------------------------------------------------------------------------
__global__ __launch_bounds__(256) void proj_gemm(
    const float* __restrict__ A, int rowsA, int Kdim, int col_off,
    const float* __restrict__ wf, const float* __restrict__ wb,
    const float* __restrict__ bf1, const float* __restrict__ bf2,
    const float* __restrict__ bb1, const float* __restrict__ bb2,
    __hip_bfloat16* __restrict__ out, int add_bias) {
  __shared__ __align__(16) __hip_bfloat16 As[128][40];
  __shared__ __align__(16) __hip_bfloat16 Bs[256][40];
  const int tid = threadIdx.x;
  const int m0 = blockIdx.x * 128, n0 = blockIdx.y * 256;
  const int lane = tid & 63, wave = tid >> 6;
  const int quad = lane >> 4, lm = lane & 15;
  float4v acc[2][16] = {};
  const int ksteps = (Kdim + 31) >> 5;
  const int r2 = tid >> 1, cbase = (tid & 1) << 4;
  const int rb = tid >> 4, cb = (tid & 15) * 2;
  for (int ks = 0; ks < ksteps; ++ks) {
    const int k0 = ks << 5;
#pragma unroll
    for (int e2 = 0; e2 < 8; ++e2) {
      int kk = k0 + cbase + 2 * e2;
      float b0 = 0.f, b1 = 0.f;
      if (m0 + r2 < rowsA && kk < Kdim) {
        float2 v = *(const float2*)(A + (size_t)(m0 + r2) * Kdim + kk);
        b0 = v.x;
        b1 = v.y;
      }
      As[r2][cbase + 2 * e2] = __float2bfloat16(b0);
      As[r2][cbase + 2 * e2 + 1] = __float2bfloat16(b1);
    }
#pragma unroll
    for (int j = 0; j < 16; ++j) {
      int n = n0 + rb + 16 * j;
      const float* __restrict__ wrow =
          (n < 1024) ? (wf + n * 450 + col_off) : (wb + (n - 1024) * 450 + col_off);
      int kk = k0 + cb;
      float b0 = 0.f, b1 = 0.f;
      if (kk < Kdim) {
        float2 v = *(const float2*)(wrow + kk);
        b0 = v.x;
        b1 = v.y;
      }
      Bs[rb + 16 * j][cb] = __float2bfloat16(b0);
      Bs[rb + 16 * j][cb + 1] = __float2bfloat16(b1);
    }
    __syncthreads();
    short8 af0 = *(const short8*)(&As[wave * 32 + lm][quad * 8]);
    short8 af1 = *(const short8*)(&As[wave * 32 + 16 + lm][quad * 8]);
#pragma unroll
    for (int t = 0; t < 16; ++t) {
      short8 bf = *(const short8*)(&Bs[t * 16 + lm][quad * 8]);
      acc[0][t] = __builtin_amdgcn_mfma_f32_16x16x32_bf16(af0, bf, acc[0][t], 0, 0, 0);
      acc[1][t] = __builtin_amdgcn_mfma_f32_16x16x32_bf16(af1, bf, acc[1][t], 0, 0, 0);
    }
    __syncthreads();
  }
#pragma unroll
  for (int mg = 0; mg < 2; ++mg) {
#pragma unroll
    for (int t = 0; t < 16; ++t) {
#pragma unroll
      for (int rr = 0; rr < 4; ++rr) {
        int m = m0 + wave * 32 + mg * 16 + quad * 4 + rr;
        int col = n0 + t * 16 + lm;
        if (m < rowsA) {
          float v = acc[mg][t][rr];
          if (add_bias)
            v += (col < 1024) ? (bf1[col] + bf2[col]) : (bb1[col - 1024] + bb2[col - 1024]);
          int dir = col >> 10, rq = col & 1023;
          int gate = rq >> 8, u = rq & 255;
          out[m * 2048 + dir * 1024 + u * 4 + gate] = __float2bfloat16(v);
        }
      }
    }
  }
}

// ---------------------------------------------------------------------------
// Kernel P: pre-sum pinyin + tag projections: pg[p*20+g] = pin[p] + tag[g].
// ---------------------------------------------------------------------------
__global__ __launch_bounds__(256) void pgsum_kernel(
    const __hip_bfloat16* __restrict__ pin, const __hip_bfloat16* __restrict__ tag,
    __hip_bfloat16* __restrict__ pg) {
  const int r = blockIdx.x;
  const int p = r / 20, g = r - p * 20;
  const int i = threadIdx.x;  // 256 threads x 8 bf16 = 2048
  const short8 va = *(const short8*)(pin + (size_t)p * 2048 + i * 8);
  const short8 vb = *(const short8*)(tag + (size_t)g * 2048 + i * 8);
  short8 vo;
#pragma unroll
  for (int j = 0; j < 8; ++j) {
    float a = __uint_as_float(((unsigned)(unsigned short)va[j]) << 16);
    float b = __uint_as_float(((unsigned)(unsigned short)vb[j]) << 16);
    __hip_bfloat16 o = __float2bfloat16(a + b);
    vo[j] = *(short*)&o;
  }
  *(short8*)(pg + (size_t)r * 2048 + i * 8) = vo;
}

// ---------------------------------------------------------------------------
// Kernel B (R20): R19 + s_setprio(1) around the MFMA cluster (T5).
// Diagnosis: 2810 cy/step = 1169 MFMA + 490 VALU + ~1150 idle. The 8 waves
// are barrier-locked into the same phase: both waves/SIMD issue MFMAs
// together (pipe serializes), then both do gate math together (MFMA pipe
// idle), then both stall on transcendental dep chains together. setprio(1)
// during MFMA lets one wave drain its 32 MFMAs back-to-back, drop prio, and
// run its gate VALU *under* the other wave's MFMA phase -- converting
// phase-serial (1280+490+stall) into overlapped (~640+640 with gates
// underneath). This is the T5 mechanism: it needs phase diversity, which
// the priority asymmetry itself creates here.
// ---------------------------------------------------------------------------
template <int USE_PG>
__global__ __launch_bounds__(512, 2) void lstm_kernel(
    const unsigned int* __restrict__ wq, const float* __restrict__ wsc,
    const int* __restrict__ x, const int* __restrict__ ptags, const int* __restrict__ gtags,
    const char* __restrict__ char_proj, const char* __restrict__ pin_proj,
    const char* __restrict__ tag_proj, const char* __restrict__ pg_proj,
    __hip_bfloat16* __restrict__ h_out) {
  extern __shared__ __align__(16) char smem[];
  __hip_bfloat16* hist = (__hip_bfloat16*)smem;  // 32*256*2 = 16384
  char* hqb = smem + 16384;                      // 2 x 272 (256 i8 h + pad)

  const int tid = threadIdx.x;
  const int w = tid >> 6, lane = tid & 63;
  const int quad = lane >> 4, lm = lane & 15;
  const int sel = lm >> 1;                // 0..7
  const int mt = sel >> 2, rr = sel & 3;  // runtime, used with literal idx only
  const int unit = w * 32 + mt * 16 + quad * 4 + rr;
  const int chain = blockIdx.x;
  const int dir = chain >> 7;
  const int b = chain & 127;
  const int boff = b * 512;

  if (tid < 34) ((uint4*)hqb)[tid] = make_uint4(0, 0, 0, 0);

  // weight fragments (MFMA A): Wf[g][m][kt], row = g*256 + w*32 + m*16 + lm
  const unsigned int* __restrict__ wqd = wq + (size_t)dir * 65536;
  int4v Wf[4][2][4];
#pragma unroll
  for (int g = 0; g < 4; ++g)
#pragma unroll
    for (int m = 0; m < 2; ++m) {
      const int row = g * 256 + w * 32 + m * 16 + lm;
#pragma unroll
      for (int kt = 0; kt < 4; ++kt)
        Wf[g][m][kt] = *(const int4v*)(wqd + row * 64 + kt * 16 + quad * 4);
    }
  float sc4[4];
#pragma unroll
  for (int g = 0; g < 4; ++g) sc4[g] = wsc[dir * 1024 + g * 256 + unit];
  __syncthreads();

  const int pre_off = dir * 2048 + unit * 8;  // byte offset into proj rows
  float cst = 0.f;

  // prefetch rotation: indices 2 steps ahead (scalar), gathers 1 step ahead
  int t_cur = dir ? 511 : 0;
  int t_nxt = dir ? 510 : 1;
  uint2 vc, vp, vg;
  int xn, pgn, pn, gn;
  {
    int xc = x[boff + t_cur], pc = ptags[boff + t_cur], gc = gtags[boff + t_cur];
    vc = *(const uint2*)(char_proj + (size_t)xc * 4096 + pre_off);
    if (USE_PG) {
      vp = *(const uint2*)(pg_proj + (size_t)(pc * 20 + gc) * 4096 + pre_off);
    } else {
      vp = *(const uint2*)(pin_proj + (size_t)pc * 4096 + pre_off);
      vg = *(const uint2*)(tag_proj + (size_t)gc * 4096 + pre_off);
    }
    xn = x[boff + t_nxt];
    pn = ptags[boff + t_nxt];
    gn = gtags[boff + t_nxt];
    if (USE_PG) pgn = pn * 20 + gn;
  }

  // prologue: Bv(0) from buffer 0 (h(-1) = 0)
  int4v Bv[4];
#pragma unroll
  for (int kt = 0; kt < 4; ++kt)
    Bv[kt] = *(const int4v*)(hqb + kt * 64 + quad * 16);

  for (int s = 0; s < 512; ++s) {
    const int nxt = (s & 1) ^ 1;
    const uint2 cv = vc, pv = vp, gv = vg;
    const int t_fut = dir ? (t_nxt > 0 ? t_nxt - 1 : 0) : (t_nxt < 511 ? t_nxt + 1 : 511);
    // issue next-step gathers + next-next indices (independent of MFMA)
    vc = *(const uint2*)(char_proj + (size_t)xn * 4096 + pre_off);
    if (USE_PG) {
      vp = *(const uint2*)(pg_proj + (size_t)pgn * 4096 + pre_off);
    } else {
      vp = *(const uint2*)(pin_proj + (size_t)pn * 4096 + pre_off);
      vg = *(const uint2*)(tag_proj + (size_t)gn * 4096 + pre_off);
    }
    xn = x[boff + t_fut];
    pn = ptags[boff + t_fut];
    gn = gtags[boff + t_fut];
    if (USE_PG) pgn = pn * 20 + gn;

    // MFMA cluster under raised priority: the first wave to win the pipe
    // drains all 32 back-to-back, drops prio, and runs its gate math under
    // the other wave's MFMA phase.
    int4v acc[4][2] = {};
    __builtin_amdgcn_s_setprio(1);
#pragma unroll
    for (int kt = 0; kt < 4; ++kt) {
#pragma unroll
      for (int g = 0; g < 4; ++g)
#pragma unroll
        for (int m = 0; m < 2; ++m)
          acc[g][m] = __builtin_amdgcn_mfma_i32_16x16x64_i8(Wf[g][m][kt], Bv[kt], acc[g][m], 0, 0, 0);
    }
    __builtin_amdgcn_s_setprio(0);

    // gate math: this lane's unit; acc component picked by (mt, rr)
    int ai = mt ? sel4_(acc[0][1], rr) : sel4_(acc[0][0], rr);
    int af = mt ? sel4_(acc[1][1], rr) : sel4_(acc[1][0], rr);
    int ag = mt ? sel4_(acc[2][1], rr) : sel4_(acc[2][0], rr);
    int ao = mt ? sel4_(acc[3][1], rr) : sel4_(acc[3][0], rr);
    float gi, gf, gg, go;
    if (USE_PG) {
      gi = bflo(cv.x) + bflo(pv.x) + (float)ai * sc4[0];
      gf = bfhi(cv.x) + bfhi(pv.x) + (float)af * sc4[1];
      gg = bflo(cv.y) + bflo(pv.y) + (float)ag * sc4[2];
      go = bfhi(cv.y) + bfhi(pv.y) + (float)ao * sc4[3];
    } else {
      gi = bflo(cv.x) + bflo(pv.x) + bflo(gv.x) + (float)ai * sc4[0];
      gf = bfhi(cv.x) + bfhi(pv.x) + bfhi(gv.x) + (float)af * sc4[1];
      gg = bflo(cv.y) + bflo(pv.y) + bflo(gv.y) + (float)ag * sc4[2];
      go = bfhi(cv.y) + bfhi(pv.y) + bfhi(gv.y) + (float)ao * sc4[3];
    }
    cst = sigmoidf_(gf) * cst + sigmoidf_(gi) * tanhf_(gg);
    float hval = sigmoidf_(go) * tanhf_(cst);
    if (!(lm & 1)) {  // even lm lanes cover all 256 units exactly once
      ((signed char*)hqb)[nxt * 272 + unit] = (signed char)(int)rintf(hval * 127.f);
    }
    barrier_lgkm();
    // read Bv for step s+1 IMMEDIATELY (latency hides under the loop tail)
#pragma unroll
    for (int kt = 0; kt < 4; ++kt)
      Bv[kt] = *(const int4v*)(hqb + nxt * 272 + kt * 64 + quad * 16);
    // bf16 history write (post-barrier; ordered before flush by barrier below)
    if (!(lm & 1)) hist[(s & 31) * 256 + unit] = __float2bfloat16(hval);
    if ((s & 15) == 15) {
      barrier_lgkm();  // all waves' hist writes visible before flush reads
      const int slotBase = (s & 31) & ~15;
      const int sBase = s - 15;
      const int row = tid >> 5;  // 512 threads: 16 steps x 32 uint4
      const int col16 = tid & 31;
      uint4 v = *(const uint4*)((const char*)hist + (slotBase + row) * 512 + col16 * 16);
      int step_r = sBase + row;
      int t_r = dir ? (511 - step_r) : step_r;
      *(uint4*)((char*)h_out + ((size_t)(chain * 512 + t_r) * 256) * 2 + col16 * 16) = v;
    }
    t_cur = t_nxt;
    t_nxt = t_fut;
  }
}

// ---------------------------------------------------------------------------
// Kernel C: emissions GEMM. em[b*512+t][k] = Hcat[n]·w_out[k] + b_out[k]
// ---------------------------------------------------------------------------
__global__ __launch_bounds__(256) void emis_kernel(
    const __hip_bfloat16* __restrict__ h_glob, const float* __restrict__ w_out,
    const float* __restrict__ b_out, float* __restrict__ em) {
  __shared__ __align__(16) __hip_bfloat16 As[64][40];
  __shared__ __align__(16) __hip_bfloat16 Bs[32][40];
  const int tid = threadIdx.x;
  const int n0 = blockIdx.x * 64;
  const int lane = tid & 63, wave = tid >> 6, quad = lane >> 4, lm = lane & 15;
  float4v acc[2] = {};
  const int r = tid >> 2, c0 = (tid & 3) << 3;
  const int rb = tid >> 3, cb = (tid & 7) << 2;
  for (int ks = 0; ks < 16; ++ks) {
    const int j0 = ks * 32;
    const int dirk = j0 >> 8, jin = j0 & 255;
    const int n = n0 + r, bb = n >> 9, tt = n & 511;
    const uint4* src =
        (const uint4*)(h_glob + ((size_t)(dirk * 128 + bb) * 512 + tt) * 256 + jin + c0);
    *(uint4*)(&As[r][c0]) = *src;
#pragma unroll
    for (int e = 0; e < 4; ++e) {
      float v = (rb < 20) ? w_out[rb * 512 + j0 + cb + e] : 0.f;
      Bs[rb][cb + e] = __float2bfloat16(v);
    }
    __syncthreads();
    short8 af = *(const short8*)(&As[wave * 16 + lm][quad * 8]);
#pragma unroll
    for (int t2 = 0; t2 < 2; ++t2) {
      short8 bf = *(const short8*)(&Bs[t2 * 16 + lm][quad * 8]);
      acc[t2] = __builtin_amdgcn_mfma_f32_16x16x32_bf16(af, bf, acc[t2], 0, 0, 0);
    }
    __syncthreads();
  }
#pragma unroll
  for (int t2 = 0; t2 < 2; ++t2) {
#pragma unroll
    for (int rr = 0; rr < 4; ++rr) {
      int col = t2 * 16 + lm;
      if (col < 20) {
        int n = n0 + wave * 16 + quad * 4 + rr;
        em[(size_t)n * 20 + col] = acc[t2][rr] + b_out[col];
      }
    }
  }
}

// ---------------------------------------------------------------------------
// Kernel D: CRF forward NLL. 1 wave per batch element, readlane broadcast.
// ---------------------------------------------------------------------------
__global__ __launch_bounds__(64) void crf_kernel(
    const float* __restrict__ em, const int* __restrict__ y,
    const float* __restrict__ start_trans, const float* __restrict__ end_trans,
    const float* __restrict__ trans, float* __restrict__ partials) {
  const int b = blockIdx.x;
  const int lane = threadIdx.x;
  const int jj = lane < 20 ? lane : 19;
  const bool act = lane < 20;
  const float* __restrict__ emb = em + (size_t)b * 512 * 20;
  const int* __restrict__ yb = y + b * 512;

  float s_part = 0.f;
#pragma unroll
  for (int i = 0; i < 8; ++i) {
    int t = lane + 64 * i;
    int yc = yb[t];
    float v = emb[t * 20 + yc];
    v += (t == 0) ? start_trans[yc] : trans[yb[t - 1] * 20 + yc];
    s_part += v;
  }
#pragma unroll
  for (int k = 32; k >= 1; k >>= 1) s_part += __shfl_xor(s_part, k, 64);
  float score = s_part + end_trans[yb[511]];

  float ET[20];
#pragma unroll
  for (int i = 0; i < 20; ++i) ET[i] = __expf(trans[i * 20 + jj]);
  float alpha = act ? (start_trans[jj] + emb[jj]) : -1e30f;
  float P = alpha;
#pragma unroll
  for (int k = 32; k >= 1; k >>= 1) P = fmaxf(P, __shfl_xor(P, k, 64));

  float eC = emb[1 * 20 + jj];
  float eN = emb[2 * 20 + jj];
  for (int t = 1; t < 512; ++t) {
    if ((t & 15) == 0) {
      P = alpha;
#pragma unroll
      for (int k = 32; k >= 1; k >>= 1) P = fmaxf(P, __shfl_xor(P, k, 64));
    }
    float ex = __expf(alpha - P);
    float s0 = 0.f, s1 = 0.f;
#pragma unroll
    for (int i = 0; i < 20; i += 2) {
      float e0 = __int_as_float(__builtin_amdgcn_readlane(__float_as_int(ex), i));
      float e1 = __int_as_float(__builtin_amdgcn_readlane(__float_as_int(ex), i + 1));
      s0 = fmaf(e0, ET[i], s0);
      s1 = fmaf(e1, ET[i + 1], s1);
    }
    int tf = t + 2 < 512 ? t + 2 : 511;
    float eF = emb[tf * 20 + jj];
    if (act) alpha = P + __logf(s0 + s1) + eC;
    eC = eN;
    eN = eF;
  }
  float v = act ? (alpha + end_trans[jj]) : -1e30f;
  float Pz = v;
#pragma unroll
  for (int k = 32; k >= 1; k >>= 1) Pz = fmaxf(Pz, __shfl_xor(Pz, k, 64));
  float e2 = __expf(v - Pz);
#pragma unroll
  for (int k = 32; k >= 1; k >>= 1) e2 += __shfl_xor(e2, k, 64);
  float logZ = Pz + __logf(e2);
  if (lane == 0) partials[b] = logZ - score;
}

__global__ __launch_bounds__(128) void reduce_kernel(const float* __restrict__ partials,
                                                     float* __restrict__ out) {
  const int tid = threadIdx.x;
  float v = partials[tid];
#pragma unroll
  for (int k = 32; k >= 1; k >>= 1) v += __shfl_xor(v, k, 64);
  __shared__ float tmp[2];
  if ((tid & 63) == 0) tmp[tid >> 6] = v;
  __syncthreads();
  if (tid == 0) out[0] = tmp[0] + tmp[1];
}

// ---------------------------------------------------------------------------
extern "C" void kernel_launch(void* const* d_in, const int* in_sizes, int n_in,
                              void* d_out, int out_size, void* d_ws, size_t ws_size,
                              hipStream_t stream) {
  const int* x = (const int*)d_in[0];
  const int* y = (const int*)d_in[1];
  const int* pre_tags = (const int*)d_in[2];
  const int* pinyin_tags = (const int*)d_in[3];
  const float* char_emb = (const float*)d_in[5];
  const float* tag_emb = (const float*)d_in[6];
  const float* pinyin_emb = (const float*)d_in[7];
  const float* w_ih_f = (const float*)d_in[8];
  const float* w_hh_f = (const float*)d_in[9];
  const float* b_ih_f = (const float*)d_in[10];
  const float* b_hh_f = (const float*)d_in[11];
  const float* w_ih_b = (const float*)d_in[12];
  const float* w_hh_b = (const float*)d_in[13];
  const float* b_ih_b = (const float*)d_in[14];
  const float* b_hh_b = (const float*)d_in[15];
  const float* w_out = (const float*)d_in[16];
  const float* b_out = (const float*)d_in[17];
  const float* start_trans = (const float*)d_in[18];
  const float* end_trans = (const float*)d_in[19];
  const float* trans = (const float*)d_in[20];

  char* ws = (char*)d_ws;
  __hip_bfloat16* char_proj = (__hip_bfloat16*)(ws);            // 10002*2048*2 = 40968192
  __hip_bfloat16* pin_proj = (__hip_bfloat16*)(ws + 40968192);  // 500*2048*2  = 2048000
  __hip_bfloat16* tag_proj = (__hip_bfloat16*)(ws + 43016192);  // 20*2048*2   = 81920
  __hip_bfloat16* h_glob = (__hip_bfloat16*)(ws + 43098112);    // 2*128*512*256*2 = 67108864
  float* em = (float*)(ws + 110206976);                         // 65536*20*4 = 5242880
  float* partials = (float*)(ws + 115449856);                   // 128*4
  // wq/wsc live inside the em region (em is written only after lstm finishes)
  unsigned int* wq = (unsigned int*)(ws + 110206976);           // 2*1024*64*4 = 524288
  float* wsc = (float*)(ws + 110206976 + 524288);               // 2048*4
  // optional presummed pinyin+tag table (runtime-gated on ws_size)
  __hip_bfloat16* pg_proj = (__hip_bfloat16*)(ws + 115450368);  // 10000*2048*2 = 40960000
  const bool use_pg = ws_size >= (size_t)115450368 + 40960000;

  wquant_kernel<<<512, 256, 0, stream>>>(w_hh_f, w_hh_b, wq, wsc);

  proj_gemm<<<dim3(79, 8), 256, 0, stream>>>(char_emb, 10002, 300, 0, w_ih_f, w_ih_b,
                                             nullptr, nullptr, nullptr, nullptr, char_proj, 0);
  proj_gemm<<<dim3(4, 8), 256, 0, stream>>>(pinyin_emb, 500, 100, 300, w_ih_f, w_ih_b,
                                            nullptr, nullptr, nullptr, nullptr, pin_proj, 0);
  proj_gemm<<<dim3(1, 8), 256, 0, stream>>>(tag_emb, 20, 50, 400, w_ih_f, w_ih_b,
                                            b_ih_f, b_hh_f, b_ih_b, b_hh_b, tag_proj, 1);
  if (use_pg) pgsum_kernel<<<10000, 256, 0, stream>>>(pin_proj, tag_proj, pg_proj);

  const int lstm_lds = 16928;  // 16384 hist + 544 hq double buffer
  if (use_pg) {
    hipFuncSetAttribute((const void*)lstm_kernel<1>, hipFuncAttributeMaxDynamicSharedMemorySize,
                        lstm_lds);
    lstm_kernel<1><<<256, 512, lstm_lds, stream>>>(wq, wsc, x, pinyin_tags, pre_tags,
                                                   (const char*)char_proj, (const char*)pin_proj,
                                                   (const char*)tag_proj, (const char*)pg_proj,
                                                   h_glob);
  } else {
    hipFuncSetAttribute((const void*)lstm_kernel<0>, hipFuncAttributeMaxDynamicSharedMemorySize,
                        lstm_lds);
    lstm_kernel<0><<<256, 512, lstm_lds, stream>>>(wq, wsc, x, pinyin_tags, pre_tags,
                                                   (const char*)char_proj, (const char*)pin_proj,
                                                   (const char*)tag_proj, (const char*)pg_proj,
                                                   h_glob);
  }

  emis_kernel<<<1024, 256, 0, stream>>>(h_glob, w_out, b_out, em);
  crf_kernel<<<128, 64, 0, stream>>>(em, y, start_trans, end_trans, trans, partials);
  reduce_kernel<<<1, 128, 0, stream>>>(partials, (float*)d_out);
}